// Round 1
// baseline (2194.354 us; speedup 1.0000x reference)
//
#include <hip/hip_runtime.h>

#define NVEC 65536   // B*H*W = 64*32*32
#define KCB  1024
#define DIM  128
#define HW   1024    // H*W

// ---------------- cc[k] = ||codebook[k]||^2 ; also zero loss accumulator ----
__global__ void k_cc(const float* __restrict__ cb, float* __restrict__ cc,
                     float* __restrict__ loss_sum) {
  const int k = blockIdx.x * blockDim.x + threadIdx.x;
  if (k == 0) *loss_sum = 0.f;
  if (k < KCB) {
    const float4* row = (const float4*)(cb + k * DIM);
    float s = 0.f;
#pragma unroll 8
    for (int j = 0; j < DIM / 4; ++j) {
      const float4 v = row[j];
      s = fmaf(v.x, v.x, s); s = fmaf(v.y, v.y, s);
      s = fmaf(v.z, v.z, s); s = fmaf(v.w, v.w, s);
    }
    cc[k] = s;
  }
}

// ---------------- argmin kernel: 64 rows x all 1024 codes per block --------
// z_flat[n][d] = z[b*131072 + d*1024 + (n&1023)], n = b*1024 + h*32 + w
__global__ __launch_bounds__(256, 2) void k_argmin(
    const float* __restrict__ z, const float* __restrict__ cb,
    const float* __restrict__ cc, float* __restrict__ idx_out) {
  __shared__ float As[DIM][64];   // [d][n-in-tile]
  __shared__ float Bs[DIM][64];   // [d][k-in-tile]
  __shared__ float zzs[64];
  const int tid = threadIdx.x;
  const int n0 = blockIdx.x * 64;                  // 64 rows, same b (64|1024)
  const float* zb = z + (n0 >> 10) * (DIM * HW) + (n0 & (HW - 1));
  // stage A tile: [128 d][64 hw], coalesced 256B segments per d-row
  {
    const int hw = (tid & 15) * 4;
    const int d0 = tid >> 4;
#pragma unroll
    for (int j = 0; j < 8; ++j) {
      const int d = d0 + 16 * j;
      const float4 v = *(const float4*)(zb + d * HW + hw);
      *(float4*)&As[d][hw] = v;
    }
  }
  __syncthreads();
  if (tid < 64) {                                   // zz per row from LDS
    float s = 0.f;
#pragma unroll 16
    for (int d = 0; d < DIM; ++d) { const float v = As[d][tid]; s = fmaf(v, v, s); }
    zzs[tid] = s;
  }
  const int ty = tid >> 4, tx = tid & 15;           // ty: 4 n-rows, tx: 4 k-cols
  float best[4] = {1e30f, 1e30f, 1e30f, 1e30f};
  int bestk[4] = {0, 0, 0, 0};
  for (int kt = 0; kt < KCB / 64; ++kt) {
    const int k0 = kt * 64;
    {                                               // stage B tile transposed
      const int k = tid >> 2;
      const int dc = (tid & 3) * 4;
      const float* cbr = cb + (k0 + k) * DIM;
#pragma unroll
      for (int j = 0; j < 8; ++j) {
        const int d = dc + 16 * j;
        const float4 v = *(const float4*)(cbr + d);
        Bs[d + 0][k] = v.x; Bs[d + 1][k] = v.y;
        Bs[d + 2][k] = v.z; Bs[d + 3][k] = v.w;
      }
    }
    __syncthreads();                                // also orders zzs (kt==0)
    float acc[4][4] = {};
#pragma unroll 8
    for (int d = 0; d < DIM; ++d) {
      const float4 a = *(const float4*)&As[d][ty * 4];
      const float4 b = *(const float4*)&Bs[d][tx * 4];
      acc[0][0] = fmaf(a.x, b.x, acc[0][0]); acc[0][1] = fmaf(a.x, b.y, acc[0][1]);
      acc[0][2] = fmaf(a.x, b.z, acc[0][2]); acc[0][3] = fmaf(a.x, b.w, acc[0][3]);
      acc[1][0] = fmaf(a.y, b.x, acc[1][0]); acc[1][1] = fmaf(a.y, b.y, acc[1][1]);
      acc[1][2] = fmaf(a.y, b.z, acc[1][2]); acc[1][3] = fmaf(a.y, b.w, acc[1][3]);
      acc[2][0] = fmaf(a.z, b.x, acc[2][0]); acc[2][1] = fmaf(a.z, b.y, acc[2][1]);
      acc[2][2] = fmaf(a.z, b.z, acc[2][2]); acc[2][3] = fmaf(a.z, b.w, acc[2][3]);
      acc[3][0] = fmaf(a.w, b.x, acc[3][0]); acc[3][1] = fmaf(a.w, b.y, acc[3][1]);
      acc[3][2] = fmaf(a.w, b.z, acc[3][2]); acc[3][3] = fmaf(a.w, b.w, acc[3][3]);
    }
    const float4 c4 = *(const float4*)(cc + k0 + tx * 4);
#pragma unroll
    for (int i = 0; i < 4; ++i) {
      const float zz = zzs[ty * 4 + i];
      const float dj0 = (zz + c4.x) - 2.f * acc[i][0];
      const float dj1 = (zz + c4.y) - 2.f * acc[i][1];
      const float dj2 = (zz + c4.z) - 2.f * acc[i][2];
      const float dj3 = (zz + c4.w) - 2.f * acc[i][3];
      float bd = dj0; int bk = k0 + tx * 4;         // strict <: first index wins
      if (dj1 < bd) { bd = dj1; bk = k0 + tx * 4 + 1; }
      if (dj2 < bd) { bd = dj2; bk = k0 + tx * 4 + 2; }
      if (dj3 < bd) { bd = dj3; bk = k0 + tx * 4 + 3; }
#pragma unroll
      for (int m = 1; m < 16; m <<= 1) {            // butterfly across tx group
        const float od = __shfl_xor(bd, m, 64);
        const int   ok = __shfl_xor(bk, m, 64);
        if (od < bd || (od == bd && ok < bk)) { bd = od; bk = ok; }
      }
      if (bd < best[i] || (bd == best[i] && bk < bestk[i])) { best[i] = bd; bestk[i] = bk; }
    }
    __syncthreads();                                // before Bs overwrite
  }
  if (tx == 0) {
#pragma unroll
    for (int i = 0; i < 4; ++i) idx_out[n0 + ty * 4 + i] = (float)bestk[i];
  }
}

// ---------------- gather quantized + loss sum ------------------------------
__global__ void k_quant_loss(const float* __restrict__ z, const float* __restrict__ cb,
                             const float* __restrict__ idx_f, float* __restrict__ out0,
                             float* __restrict__ loss_sum) {
  __shared__ float red[4];
  const int t = blockIdx.x * blockDim.x + threadIdx.x;   // float4 index
  const int n = t >> 5;
  const int d4 = t & 31;
  const int k = (int)idx_f[n];
  const float4 q  = *(const float4*)(cb + k * DIM + d4 * 4);
  const float4 zv = *(const float4*)(z + ((size_t)t << 2));
  *(float4*)(out0 + ((size_t)t << 2)) = q;
  const float dx = q.x - zv.x, dy = q.y - zv.y, dz = q.z - zv.z, dw = q.w - zv.w;
  float s = dx * dx + dy * dy + dz * dz + dw * dw;
#pragma unroll
  for (int m = 32; m; m >>= 1) s += __shfl_xor(s, m, 64);
  const int lane = threadIdx.x & 63, wv = threadIdx.x >> 6;
  if (lane == 0) red[wv] = s;
  __syncthreads();
  if (threadIdx.x == 0) atomicAdd(loss_sum, red[0] + red[1] + red[2] + red[3]);
}

// ---------------- init EMA outputs with decayed old state ------------------
__global__ void k_init_ema(const float* __restrict__ ema_count,
                           const float* __restrict__ ema_weight,
                           float* __restrict__ out5, float* __restrict__ out6) {
  const int i = blockIdx.x * blockDim.x + threadIdx.x;
  out6[i] = 0.99f * ema_weight[i];
  if (i < KCB) out5[i] = 0.99f * ema_count[i];
}

// ---------------- scatter dw and counts (atomics) --------------------------
__global__ void k_dw(const float* __restrict__ z, const float* __restrict__ idx_f,
                     float* __restrict__ out5, float* __restrict__ out6) {
  const int n = blockIdx.x * blockDim.x + threadIdx.x;
  const int k = (int)idx_f[n];
  atomicAdd(&out5[k], 0.01f);
  const float* zr = z + (n >> 10) * (DIM * HW) + (n & (HW - 1));
  float* dwr = out6 + k * DIM;
#pragma unroll 4
  for (int d = 0; d < DIM; ++d) atomicAdd(&dwr[d], 0.01f * zr[d * HW]);
}

// ---------------- n = sum(new_ema_count) -----------------------------------
__global__ void k_reduce_n(const float* __restrict__ out5, float* __restrict__ ntot) {
  __shared__ float red[4];
  const int tid = threadIdx.x;
  float s = out5[tid] + out5[tid + 256] + out5[tid + 512] + out5[tid + 768];
#pragma unroll
  for (int m = 32; m; m >>= 1) s += __shfl_xor(s, m, 64);
  if ((tid & 63) == 0) red[tid >> 6] = s;
  __syncthreads();
  if (tid == 0) *ntot = red[0] + red[1] + red[2] + red[3];
}

// ---------------- new_codebook + losses ------------------------------------
__global__ void k_final(const float* __restrict__ out5, const float* __restrict__ out6,
                        const float* __restrict__ ntot_p, const float* __restrict__ loss_sum,
                        float* __restrict__ out4, float* __restrict__ out2,
                        float* __restrict__ out3) {
  const int i = blockIdx.x * blockDim.x + threadIdx.x;
  const float ntot = *ntot_p;
  const int k = i >> 7;
  const float w = (out5[k] + 1e-5f) / (ntot + KCB * 1e-5f) * ntot;
  out4[i] = out6[i] / w;
  if (i == 0) {
    const float lv = *loss_sum * (1.f / 8388608.f);
    *out2 = lv; *out3 = lv;
  }
}

extern "C" void kernel_launch(void* const* d_in, const int* in_sizes, int n_in,
                              void* d_out, int out_size, void* d_ws, size_t ws_size,
                              hipStream_t stream) {
  (void)in_sizes; (void)n_in; (void)out_size; (void)ws_size;
  const float* z   = (const float*)d_in[0];
  const float* cb  = (const float*)d_in[1];
  const float* emc = (const float*)d_in[2];
  const float* emw = (const float*)d_in[3];
  float* out = (float*)d_out;
  float* out0 = out;                    // quantized_st  [8388608]
  float* out1 = out + 8388608;          // idx_map (float)[65536]
  float* out2 = out + 8454144;          // commitment_loss [1]
  float* out3 = out + 8454145;          // codebook_loss   [1]
  float* out4 = out + 8454146;          // new_codebook  [131072]
  float* out5 = out + 8585218;          // new_ema_count [1024]
  float* out6 = out + 8586242;          // new_ema_weight[131072]
  float* ws  = (float*)d_ws;
  float* cc       = ws;                 // [1024]
  float* loss_sum = ws + 1024;          // [1]
  float* ntot     = ws + 1025;          // [1]

  hipLaunchKernelGGL(k_cc, dim3(4), dim3(256), 0, stream, cb, cc, loss_sum);
  hipLaunchKernelGGL(k_argmin, dim3(NVEC / 64), dim3(256), 0, stream, z, cb, cc, out1);
  hipLaunchKernelGGL(k_init_ema, dim3(512), dim3(256), 0, stream, emc, emw, out5, out6);
  hipLaunchKernelGGL(k_quant_loss, dim3(8192), dim3(256), 0, stream, z, cb, out1, out0, loss_sum);
  hipLaunchKernelGGL(k_dw, dim3(NVEC / 256), dim3(256), 0, stream, z, out1, out5, out6);
  hipLaunchKernelGGL(k_reduce_n, dim3(1), dim3(256), 0, stream, out5, ntot);
  hipLaunchKernelGGL(k_final, dim3(512), dim3(256), 0, stream, out5, out6, ntot, loss_sum,
                     out4, out2, out3);
}

// Round 2
// 680.083 us; speedup vs baseline: 3.2266x; 3.2266x over previous
//
#include <hip/hip_runtime.h>

#define NVEC 65536   // B*H*W = 64*32*32
#define KCB  1024
#define DIM  128
#define HW   1024    // H*W

// ---------------- cc[k] = ||codebook[k]||^2 ; also zero loss accumulator ----
__global__ void k_cc(const float* __restrict__ cb, float* __restrict__ cc,
                     float* __restrict__ loss_sum) {
  const int k = blockIdx.x * blockDim.x + threadIdx.x;
  if (k == 0) *loss_sum = 0.f;
  if (k < KCB) {
    const float4* row = (const float4*)(cb + k * DIM);
    float s = 0.f;
#pragma unroll 8
    for (int j = 0; j < DIM / 4; ++j) {
      const float4 v = row[j];
      s = fmaf(v.x, v.x, s); s = fmaf(v.y, v.y, s);
      s = fmaf(v.z, v.z, s); s = fmaf(v.w, v.w, s);
    }
    cc[k] = s;
  }
}

// ---------------- transpose z[b][d][hw] -> z_t[(b*1024+hw)][d] -------------
__global__ void k_transpose(const float* __restrict__ z, float* __restrict__ z_t) {
  __shared__ float tile[64][65];
  const int t = threadIdx.x;
  const int b = blockIdx.z;
  const int d0 = blockIdx.y * 64;
  const int hw0 = blockIdx.x * 64;
  const float* src = z + (size_t)b * 131072 + d0 * 1024 + hw0;
  {
    const int hw4 = (t & 15) * 4;
    const int dr = t >> 4;
#pragma unroll
    for (int j = 0; j < 4; ++j) {
      const int d = dr + 16 * j;
      const float4 v = *(const float4*)(src + d * 1024 + hw4);
      tile[d][hw4 + 0] = v.x; tile[d][hw4 + 1] = v.y;
      tile[d][hw4 + 2] = v.z; tile[d][hw4 + 3] = v.w;
    }
  }
  __syncthreads();
  float* dst = z_t + (size_t)b * 131072 + hw0 * 128 + d0;
  {
    const int d4 = (t & 31) * 4;
    const int hwr = t >> 5;
#pragma unroll
    for (int j = 0; j < 8; ++j) {
      const int hw = hwr + 8 * j;
      float4 v;
      v.x = tile[d4 + 0][hw]; v.y = tile[d4 + 1][hw];
      v.z = tile[d4 + 2][hw]; v.w = tile[d4 + 3][hw];
      *(float4*)(dst + hw * 128 + d4) = v;
    }
  }
}

// ---------------- argmin kernel: 64 rows x all 1024 codes per block --------
// z_flat[n][d] = z[b*131072 + d*1024 + (n&1023)], n = b*1024 + h*32 + w
__global__ __launch_bounds__(256, 2) void k_argmin(
    const float* __restrict__ z, const float* __restrict__ cb,
    const float* __restrict__ cc, float* __restrict__ idx_out) {
  __shared__ float As[DIM][64];   // [d][n-in-tile]
  __shared__ float Bs[DIM][64];   // [d][k-in-tile]
  __shared__ float zzs[64];
  const int tid = threadIdx.x;
  const int n0 = blockIdx.x * 64;                  // 64 rows, same b (64|1024)
  const float* zb = z + (n0 >> 10) * (DIM * HW) + (n0 & (HW - 1));
  {
    const int hw = (tid & 15) * 4;
    const int d0 = tid >> 4;
#pragma unroll
    for (int j = 0; j < 8; ++j) {
      const int d = d0 + 16 * j;
      const float4 v = *(const float4*)(zb + d * HW + hw);
      *(float4*)&As[d][hw] = v;
    }
  }
  __syncthreads();
  if (tid < 64) {                                   // zz per row from LDS
    float s = 0.f;
#pragma unroll 16
    for (int d = 0; d < DIM; ++d) { const float v = As[d][tid]; s = fmaf(v, v, s); }
    zzs[tid] = s;
  }
  const int ty = tid >> 4, tx = tid & 15;           // ty: 4 n-rows, tx: 4 k-cols
  float best[4] = {1e30f, 1e30f, 1e30f, 1e30f};
  int bestk[4] = {0, 0, 0, 0};
  for (int kt = 0; kt < KCB / 64; ++kt) {
    const int k0 = kt * 64;
    {                                               // stage B tile transposed
      const int k = tid >> 2;
      const int dc = (tid & 3) * 4;
      const float* cbr = cb + (k0 + k) * DIM;
#pragma unroll
      for (int j = 0; j < 8; ++j) {
        const int d = dc + 16 * j;
        const float4 v = *(const float4*)(cbr + d);
        Bs[d + 0][k] = v.x; Bs[d + 1][k] = v.y;
        Bs[d + 2][k] = v.z; Bs[d + 3][k] = v.w;
      }
    }
    __syncthreads();                                // also orders zzs (kt==0)
    float acc[4][4] = {};
#pragma unroll 8
    for (int d = 0; d < DIM; ++d) {
      const float4 a = *(const float4*)&As[d][ty * 4];
      const float4 b = *(const float4*)&Bs[d][tx * 4];
      acc[0][0] = fmaf(a.x, b.x, acc[0][0]); acc[0][1] = fmaf(a.x, b.y, acc[0][1]);
      acc[0][2] = fmaf(a.x, b.z, acc[0][2]); acc[0][3] = fmaf(a.x, b.w, acc[0][3]);
      acc[1][0] = fmaf(a.y, b.x, acc[1][0]); acc[1][1] = fmaf(a.y, b.y, acc[1][1]);
      acc[1][2] = fmaf(a.y, b.z, acc[1][2]); acc[1][3] = fmaf(a.y, b.w, acc[1][3]);
      acc[2][0] = fmaf(a.z, b.x, acc[2][0]); acc[2][1] = fmaf(a.z, b.y, acc[2][1]);
      acc[2][2] = fmaf(a.z, b.z, acc[2][2]); acc[2][3] = fmaf(a.z, b.w, acc[2][3]);
      acc[3][0] = fmaf(a.w, b.x, acc[3][0]); acc[3][1] = fmaf(a.w, b.y, acc[3][1]);
      acc[3][2] = fmaf(a.w, b.z, acc[3][2]); acc[3][3] = fmaf(a.w, b.w, acc[3][3]);
    }
    const float4 c4 = *(const float4*)(cc + k0 + tx * 4);
#pragma unroll
    for (int i = 0; i < 4; ++i) {
      const float zz = zzs[ty * 4 + i];
      const float dj0 = (zz + c4.x) - 2.f * acc[i][0];
      const float dj1 = (zz + c4.y) - 2.f * acc[i][1];
      const float dj2 = (zz + c4.z) - 2.f * acc[i][2];
      const float dj3 = (zz + c4.w) - 2.f * acc[i][3];
      float bd = dj0; int bk = k0 + tx * 4;         // strict <: first index wins
      if (dj1 < bd) { bd = dj1; bk = k0 + tx * 4 + 1; }
      if (dj2 < bd) { bd = dj2; bk = k0 + tx * 4 + 2; }
      if (dj3 < bd) { bd = dj3; bk = k0 + tx * 4 + 3; }
#pragma unroll
      for (int m = 1; m < 16; m <<= 1) {            // butterfly across tx group
        const float od = __shfl_xor(bd, m, 64);
        const int   ok = __shfl_xor(bk, m, 64);
        if (od < bd || (od == bd && ok < bk)) { bd = od; bk = ok; }
      }
      if (bd < best[i] || (bd == best[i] && bk < bestk[i])) { best[i] = bd; bestk[i] = bk; }
    }
    __syncthreads();                                // before Bs overwrite
  }
  if (tx == 0) {
#pragma unroll
    for (int i = 0; i < 4; ++i) idx_out[n0 + ty * 4 + i] = (float)bestk[i];
  }
}

// ---------------- histogram of indices (LDS-aggregated) --------------------
__global__ void k_hist(const float* __restrict__ idx_f, int* __restrict__ hist) {
  __shared__ int h[KCB];
  const int t = threadIdx.x;
#pragma unroll
  for (int j = 0; j < 4; ++j) h[t + 256 * j] = 0;
  __syncthreads();
  const int n0 = blockIdx.x * 1024;
#pragma unroll
  for (int j = 0; j < 4; ++j) {
    const int k = (int)idx_f[n0 + t + 256 * j];
    atomicAdd(&h[k], 1);
  }
  __syncthreads();
#pragma unroll
  for (int j = 0; j < 4; ++j) {
    const int v = h[t + 256 * j];
    if (v) atomicAdd(&hist[t + 256 * j], v);
  }
}

// ---------------- exclusive scan over 1024 bins (single block) -------------
__global__ void k_scan(const int* __restrict__ hist, int* __restrict__ seg,
                       int* __restrict__ cursor) {
  __shared__ int tmp[KCB];
  const int t = threadIdx.x;
  const int v = hist[t];
  tmp[t] = v;
  __syncthreads();
  for (int off = 1; off < KCB; off <<= 1) {
    int x = 0;
    if (t >= off) x = tmp[t - off];
    __syncthreads();
    if (t >= off) tmp[t] += x;
    __syncthreads();
  }
  const int incl = tmp[t];
  const int excl = incl - v;
  seg[t] = excl;
  cursor[t] = excl;
  if (t == KCB - 1) seg[KCB] = incl;
}

// ---------------- scatter n's into per-code segments -----------------------
__global__ void k_scatter(const float* __restrict__ idx_f, int* __restrict__ cursor,
                          int* __restrict__ order) {
  const int n = blockIdx.x * blockDim.x + threadIdx.x;
  const int k = (int)idx_f[n];
  const int pos = atomicAdd(&cursor[k], 1);
  order[pos] = n;
}

// ---------------- segmented reduction: dw + counts -> out5/out6 ------------
__global__ __launch_bounds__(128) void k_segreduce(
    const float* __restrict__ z_t, const int* __restrict__ seg,
    const int* __restrict__ order, const float* __restrict__ emc,
    const float* __restrict__ emw, float* __restrict__ out5,
    float* __restrict__ out6) {
  const int k = blockIdx.x, t = threadIdx.x;
  const int s0 = seg[k], s1 = seg[k + 1];
  float acc = 0.f;
  int i = s0;
  for (; i + 4 <= s1; i += 4) {
    const int n0 = order[i], n1 = order[i + 1], n2 = order[i + 2], n3 = order[i + 3];
    const float a0 = z_t[(size_t)n0 * 128 + t];
    const float a1 = z_t[(size_t)n1 * 128 + t];
    const float a2 = z_t[(size_t)n2 * 128 + t];
    const float a3 = z_t[(size_t)n3 * 128 + t];
    acc += a0 + a1 + a2 + a3;
  }
  for (; i < s1; ++i) acc += z_t[(size_t)order[i] * 128 + t];
  out6[k * 128 + t] = 0.99f * emw[k * 128 + t] + 0.01f * acc;
  if (t == 0) out5[k] = 0.99f * emc[k] + 0.01f * (float)(s1 - s0);
}

// ---------------- gather quantized + loss sum ------------------------------
__global__ void k_quant_loss(const float* __restrict__ z, const float* __restrict__ cb,
                             const float* __restrict__ idx_f, float* __restrict__ out0,
                             float* __restrict__ loss_sum) {
  __shared__ float red[4];
  const int t = blockIdx.x * blockDim.x + threadIdx.x;   // float4 index
  const int n = t >> 5;
  const int d4 = t & 31;
  const int k = (int)idx_f[n];
  const float4 q  = *(const float4*)(cb + k * DIM + d4 * 4);
  const float4 zv = *(const float4*)(z + ((size_t)t << 2));
  *(float4*)(out0 + ((size_t)t << 2)) = q;
  const float dx = q.x - zv.x, dy = q.y - zv.y, dz = q.z - zv.z, dw = q.w - zv.w;
  float s = dx * dx + dy * dy + dz * dz + dw * dw;
#pragma unroll
  for (int m = 32; m; m >>= 1) s += __shfl_xor(s, m, 64);
  const int lane = threadIdx.x & 63, wv = threadIdx.x >> 6;
  if (lane == 0) red[wv] = s;
  __syncthreads();
  if (threadIdx.x == 0) atomicAdd(loss_sum, red[0] + red[1] + red[2] + red[3]);
}

// ---------------- n = sum(new_ema_count) -----------------------------------
__global__ void k_reduce_n(const float* __restrict__ out5, float* __restrict__ ntot) {
  __shared__ float red[4];
  const int tid = threadIdx.x;
  float s = out5[tid] + out5[tid + 256] + out5[tid + 512] + out5[tid + 768];
#pragma unroll
  for (int m = 32; m; m >>= 1) s += __shfl_xor(s, m, 64);
  if ((tid & 63) == 0) red[tid >> 6] = s;
  __syncthreads();
  if (tid == 0) *ntot = red[0] + red[1] + red[2] + red[3];
}

// ---------------- new_codebook + losses ------------------------------------
__global__ void k_final(const float* __restrict__ out5, const float* __restrict__ out6,
                        const float* __restrict__ ntot_p, const float* __restrict__ loss_sum,
                        float* __restrict__ out4, float* __restrict__ out2,
                        float* __restrict__ out3) {
  const int i = blockIdx.x * blockDim.x + threadIdx.x;
  const float ntot = *ntot_p;
  const int k = i >> 7;
  const float w = (out5[k] + 1e-5f) / (ntot + KCB * 1e-5f) * ntot;
  out4[i] = out6[i] / w;
  if (i == 0) {
    const float lv = *loss_sum * (1.f / 8388608.f);
    *out2 = lv; *out3 = lv;
  }
}

extern "C" void kernel_launch(void* const* d_in, const int* in_sizes, int n_in,
                              void* d_out, int out_size, void* d_ws, size_t ws_size,
                              hipStream_t stream) {
  (void)in_sizes; (void)n_in; (void)out_size; (void)ws_size;
  const float* z   = (const float*)d_in[0];
  const float* cb  = (const float*)d_in[1];
  const float* emc = (const float*)d_in[2];
  const float* emw = (const float*)d_in[3];
  float* out = (float*)d_out;
  float* out0 = out;                    // quantized_st  [8388608]
  float* out1 = out + 8388608;          // idx_map (float)[65536]
  float* out2 = out + 8454144;          // commitment_loss [1]
  float* out3 = out + 8454145;          // codebook_loss   [1]
  float* out4 = out + 8454146;          // new_codebook  [131072]
  float* out5 = out + 8585218;          // new_ema_count [1024]
  float* out6 = out + 8586242;          // new_ema_weight[131072]
  float* ws = (float*)d_ws;
  float* cc       = ws;                 // [1024]
  float* loss_sum = ws + 1024;          // [1]
  float* ntot     = ws + 1025;          // [1]
  int* hist   = (int*)(ws + 2048);      // [1024]
  int* seg    = (int*)(ws + 3072);      // [1025]
  int* cursor = (int*)(ws + 4224);      // [1024]
  int* order  = (int*)(ws + 5248);      // [65536]
  float* z_t = out0;                    // scratch: overwritten by k_quant_loss later

  hipMemsetAsync(hist, 0, KCB * sizeof(int), stream);
  hipLaunchKernelGGL(k_cc, dim3(4), dim3(256), 0, stream, cb, cc, loss_sum);
  hipLaunchKernelGGL(k_transpose, dim3(16, 2, 64), dim3(256), 0, stream, z, z_t);
  hipLaunchKernelGGL(k_argmin, dim3(NVEC / 64), dim3(256), 0, stream, z, cb, cc, out1);
  hipLaunchKernelGGL(k_hist, dim3(64), dim3(256), 0, stream, out1, hist);
  hipLaunchKernelGGL(k_scan, dim3(1), dim3(1024), 0, stream, hist, seg, cursor);
  hipLaunchKernelGGL(k_scatter, dim3(NVEC / 256), dim3(256), 0, stream, out1, cursor, order);
  hipLaunchKernelGGL(k_segreduce, dim3(KCB), dim3(128), 0, stream, z_t, seg, order,
                     emc, emw, out5, out6);
  hipLaunchKernelGGL(k_quant_loss, dim3(8192), dim3(256), 0, stream, z, cb, out1, out0, loss_sum);
  hipLaunchKernelGGL(k_reduce_n, dim3(1), dim3(256), 0, stream, out5, ntot);
  hipLaunchKernelGGL(k_final, dim3(512), dim3(256), 0, stream, out5, out6, ntot, loss_sum,
                     out4, out2, out3);
}

// Round 3
// 478.588 us; speedup vs baseline: 4.5851x; 1.4210x over previous
//
#include <hip/hip_runtime.h>

#define NVEC 65536   // B*H*W = 64*32*32
#define KCB  1024
#define DIM  128
#define HW   1024    // H*W

typedef __bf16 b16;
typedef b16 b16x8 __attribute__((ext_vector_type(8)));
typedef float f32x16 __attribute__((ext_vector_type(16)));

static __device__ __forceinline__ unsigned short f2bf(float f) {
  unsigned int x = __float_as_uint(f);
  unsigned int r = x + 0x7fffu + ((x >> 16) & 1u);   // RNE
  return (unsigned short)(r >> 16);
}

// ---------------- cc[k] = ||codebook[k]||^2 ; also zero loss accumulator ----
__global__ void k_cc(const float* __restrict__ cb, float* __restrict__ cc,
                     float* __restrict__ loss_sum) {
  const int k = blockIdx.x * blockDim.x + threadIdx.x;
  if (k == 0) *loss_sum = 0.f;
  if (k < KCB) {
    const float4* row = (const float4*)(cb + k * DIM);
    float s = 0.f;
#pragma unroll 8
    for (int j = 0; j < DIM / 4; ++j) {
      const float4 v = row[j];
      s = fmaf(v.x, v.x, s); s = fmaf(v.y, v.y, s);
      s = fmaf(v.z, v.z, s); s = fmaf(v.w, v.w, s);
    }
    cc[k] = s;
  }
}

// ---------------- cb -> cb_t bf16 packed [kc][dchunk][code7] 16B units -----
__global__ void k_cbt(const float* __restrict__ cb, uint4* __restrict__ cbt) {
  const int t = blockIdx.x * blockDim.x + threadIdx.x;   // 16384
  const int kc = t >> 11, u = t & 2047;
  const int code7 = u & 127, dch = u >> 7;
  const float* src = cb + (kc * 128 + code7) * 128 + dch * 8;
  const float4 x = *(const float4*)src;
  const float4 y = *(const float4*)(src + 4);
  uint4 o;
  o.x = (unsigned)f2bf(x.x) | ((unsigned)f2bf(x.y) << 16);
  o.y = (unsigned)f2bf(x.z) | ((unsigned)f2bf(x.w) << 16);
  o.z = (unsigned)f2bf(y.x) | ((unsigned)f2bf(y.y) << 16);
  o.w = (unsigned)f2bf(y.z) | ((unsigned)f2bf(y.w) << 16);
  cbt[t] = o;
}

// ---------------- transpose z[b][d][hw] -> z_t[(b*1024+hw)][d] (f32) -------
__global__ void k_transpose(const float* __restrict__ z, float* __restrict__ z_t) {
  __shared__ float tile[64][65];
  const int t = threadIdx.x;
  const int b = blockIdx.z;
  const int d0 = blockIdx.y * 64;
  const int hw0 = blockIdx.x * 64;
  const float* src = z + (size_t)b * 131072 + d0 * 1024 + hw0;
  {
    const int hw4 = (t & 15) * 4;
    const int dr = t >> 4;
#pragma unroll
    for (int j = 0; j < 4; ++j) {
      const int d = dr + 16 * j;
      const float4 v = *(const float4*)(src + d * 1024 + hw4);
      tile[d][hw4 + 0] = v.x; tile[d][hw4 + 1] = v.y;
      tile[d][hw4 + 2] = v.z; tile[d][hw4 + 3] = v.w;
    }
  }
  __syncthreads();
  float* dst = z_t + (size_t)b * 131072 + hw0 * 128 + d0;
  {
    const int d4 = (t & 31) * 4;
    const int hwr = t >> 5;
#pragma unroll
    for (int j = 0; j < 8; ++j) {
      const int hw = hwr + 8 * j;
      float4 v;
      v.x = tile[d4 + 0][hw]; v.y = tile[d4 + 1][hw];
      v.z = tile[d4 + 2][hw]; v.w = tile[d4 + 3][hw];
      *(float4*)(dst + hw * 128 + d4) = v;
    }
  }
}

// ---------------- MFMA argmin: top-2 candidates per row --------------------
// block: 256 thr (4 waves), 128 rows; wave wv owns rows wv*32..wv*32+31.
// A (z rows, bf16) in registers; B (codebook) staged per 128-code chunk.
__global__ __launch_bounds__(256, 2) void k_mfma_argmin(
    const float* __restrict__ z, const uint4* __restrict__ cbt,
    const float* __restrict__ cc, int* __restrict__ cand1,
    int* __restrict__ cand2) {
  __shared__ uint4 Bs[2048];                       // 32 KiB: u = dchunk*128 + code7
  const int tid = threadIdx.x;
  const int l = tid & 63, wv = tid >> 6;
  const int g = l >> 5;                            // k-group
  const int lm = l & 31;                           // row / code lane
  const int n0 = blockIdx.x * 128;
  const int b = n0 >> 10;
  const int hw = (n0 & (HW - 1)) + wv * 32 + lm;   // this lane's row (128 | 1024)
  const float* zp = z + (size_t)b * 131072 + hw;

  // ---- A fragments: afrag[ks] holds z[row][ks*16 + g*8 + 0..7] as bf16x8
  uint4 afrag[8];
#pragma unroll
  for (int ks = 0; ks < 8; ++ks) {
    const int d0 = ks * 16 + g * 8;
    unsigned u0 = (unsigned)f2bf(zp[(d0 + 0) * 1024]) | ((unsigned)f2bf(zp[(d0 + 1) * 1024]) << 16);
    unsigned u1 = (unsigned)f2bf(zp[(d0 + 2) * 1024]) | ((unsigned)f2bf(zp[(d0 + 3) * 1024]) << 16);
    unsigned u2 = (unsigned)f2bf(zp[(d0 + 4) * 1024]) | ((unsigned)f2bf(zp[(d0 + 5) * 1024]) << 16);
    unsigned u3 = (unsigned)f2bf(zp[(d0 + 6) * 1024]) | ((unsigned)f2bf(zp[(d0 + 7) * 1024]) << 16);
    afrag[ks] = make_uint4(u0, u1, u2, u3);
  }

  float b1[16], b2[16];
  int i1[16], i2[16];
#pragma unroll
  for (int r = 0; r < 16; ++r) { b1[r] = 1e30f; b2[r] = 1e30f; i1[r] = 0; i2[r] = 1; }

  for (int kc = 0; kc < 8; ++kc) {
    __syncthreads();                               // Bs readers of prev chunk done
    // stage 32KB: 8 wave-instrs x 1KB, linear dest, linear pre-permuted source
#pragma unroll
    for (int i = 0; i < 8; ++i) {
      __builtin_amdgcn_global_load_lds(&cbt[kc * 2048 + wv * 512 + i * 64 + l],
                                       &Bs[wv * 512 + i * 64], 16, 0, 0);
    }
    float ccv[4];
#pragma unroll
    for (int f = 0; f < 4; ++f) ccv[f] = cc[kc * 128 + f * 32 + lm];
    __syncthreads();                               // all staging landed

    f32x16 acc[4] = {};
#pragma unroll
    for (int ks = 0; ks < 8; ++ks) {
      const b16x8 av = *reinterpret_cast<const b16x8*>(&afrag[ks]);
#pragma unroll
      for (int f = 0; f < 4; ++f) {
        const b16x8 bv = *reinterpret_cast<const b16x8*>(&Bs[(ks * 2 + g) * 128 + f * 32 + lm]);
        acc[f] = __builtin_amdgcn_mfma_f32_32x32x16_bf16(av, bv, acc[f], 0, 0, 0);
      }
    }
    // epilogue: merge 64 scores into running top-2 per row-slot
#pragma unroll
    for (int f = 0; f < 4; ++f) {
      const int c = kc * 128 + f * 32 + lm;
#pragma unroll
      for (int r = 0; r < 16; ++r) {
        const float s = fmaf(-2.f, acc[f][r], ccv[f]);
        const bool lt1 = s < b1[r];
        const bool lt2 = s < b2[r];
        b2[r] = lt1 ? b1[r] : (lt2 ? s : b2[r]);
        i2[r] = lt1 ? i1[r] : (lt2 ? c : i2[r]);
        b1[r] = lt1 ? s : b1[r];
        i1[r] = lt1 ? c : i1[r];
      }
    }
  }

  // final: top-2 over the 32 code-lanes (butterfly within 32-lane halves)
#pragma unroll
  for (int r = 0; r < 16; ++r) {
    float a1 = b1[r], a2 = b2[r];
    int j1 = i1[r], j2 = i2[r];
#pragma unroll
    for (int m = 1; m < 32; m <<= 1) {
      const float o1 = __shfl_xor(a1, m, 64);
      const int oj1 = __shfl_xor(j1, m, 64);
      const float o2 = __shfl_xor(a2, m, 64);
      const int oj2 = __shfl_xor(j2, m, 64);
      const bool sw = (o1 < a1) || (o1 == a1 && oj1 < j1);
      const float w1 = sw ? o1 : a1; const int wj1 = sw ? oj1 : j1;
      float l1 = sw ? a1 : o1; int lj1 = sw ? j1 : oj1;   // loser of bests
      if (a2 < l1 || (a2 == l1 && j2 < lj1)) { l1 = a2; lj1 = j2; }
      if (o2 < l1 || (o2 == l1 && oj2 < lj1)) { l1 = o2; lj1 = oj2; }
      a1 = w1; j1 = wj1; a2 = l1; j2 = lj1;
    }
    if (lm == 0) {
      const int rowg = n0 + wv * 32 + (r & 3) + 8 * (r >> 2) + 4 * g;
      cand1[rowg] = j1;
      cand2[rowg] = j2;
    }
  }
}

// ---------------- exact f32 rescore of the two candidates ------------------
__global__ void k_rescore(const float* __restrict__ z, const float* __restrict__ cb,
                          const float* __restrict__ ccw, const int* __restrict__ cand1,
                          const int* __restrict__ cand2, float* __restrict__ out1) {
  const int n = blockIdx.x * blockDim.x + threadIdx.x;
  const int b = n >> 10, hw = n & (HW - 1);
  const int k1 = cand1[n], k2 = cand2[n];
  const float* zp = z + (size_t)b * 131072 + hw;
  const float* c1 = cb + k1 * DIM;
  const float* c2 = cb + k2 * DIM;
  float d1 = 0.f, d2 = 0.f;
#pragma unroll 8
  for (int d = 0; d < DIM; ++d) {
    const float zv = zp[d * 1024];
    d1 = fmaf(zv, c1[d], d1);
    d2 = fmaf(zv, c2[d], d2);
  }
  const float s1 = fmaf(-2.f, d1, ccw[k1]);
  const float s2 = fmaf(-2.f, d2, ccw[k2]);
  const int kw = (s2 < s1 || (s2 == s1 && k2 < k1)) ? k2 : k1;
  out1[n] = (float)kw;
}

// ---------------- histogram of indices (LDS-aggregated) --------------------
__global__ void k_hist(const float* __restrict__ idx_f, int* __restrict__ hist) {
  __shared__ int h[KCB];
  const int t = threadIdx.x;
#pragma unroll
  for (int j = 0; j < 4; ++j) h[t + 256 * j] = 0;
  __syncthreads();
  const int n0 = blockIdx.x * 1024;
#pragma unroll
  for (int j = 0; j < 4; ++j) {
    const int k = (int)idx_f[n0 + t + 256 * j];
    atomicAdd(&h[k], 1);
  }
  __syncthreads();
#pragma unroll
  for (int j = 0; j < 4; ++j) {
    const int v = h[t + 256 * j];
    if (v) atomicAdd(&hist[t + 256 * j], v);
  }
}

// ---------------- exclusive scan over 1024 bins (single block) -------------
__global__ void k_scan(const int* __restrict__ hist, int* __restrict__ seg,
                       int* __restrict__ cursor) {
  __shared__ int tmp[KCB];
  const int t = threadIdx.x;
  const int v = hist[t];
  tmp[t] = v;
  __syncthreads();
  for (int off = 1; off < KCB; off <<= 1) {
    int x = 0;
    if (t >= off) x = tmp[t - off];
    __syncthreads();
    if (t >= off) tmp[t] += x;
    __syncthreads();
  }
  const int incl = tmp[t];
  const int excl = incl - v;
  seg[t] = excl;
  cursor[t] = excl;
  if (t == KCB - 1) seg[KCB] = incl;
}

// ---------------- scatter n's into per-code segments -----------------------
__global__ void k_scatter(const float* __restrict__ idx_f, int* __restrict__ cursor,
                          int* __restrict__ order) {
  const int n = blockIdx.x * blockDim.x + threadIdx.x;
  const int k = (int)idx_f[n];
  const int pos = atomicAdd(&cursor[k], 1);
  order[pos] = n;
}

// ---------------- segmented reduction: dw + counts -> out5/out6 ------------
__global__ __launch_bounds__(128) void k_segreduce(
    const float* __restrict__ z_t, const int* __restrict__ seg,
    const int* __restrict__ order, const float* __restrict__ emc,
    const float* __restrict__ emw, float* __restrict__ out5,
    float* __restrict__ out6) {
  const int k = blockIdx.x, t = threadIdx.x;
  const int s0 = seg[k], s1 = seg[k + 1];
  float acc = 0.f;
  int i = s0;
  for (; i + 4 <= s1; i += 4) {
    const int n0 = order[i], n1 = order[i + 1], n2 = order[i + 2], n3 = order[i + 3];
    const float a0 = z_t[(size_t)n0 * 128 + t];
    const float a1 = z_t[(size_t)n1 * 128 + t];
    const float a2 = z_t[(size_t)n2 * 128 + t];
    const float a3 = z_t[(size_t)n3 * 128 + t];
    acc += a0 + a1 + a2 + a3;
  }
  for (; i < s1; ++i) acc += z_t[(size_t)order[i] * 128 + t];
  out6[k * 128 + t] = 0.99f * emw[k * 128 + t] + 0.01f * acc;
  if (t == 0) out5[k] = 0.99f * emc[k] + 0.01f * (float)(s1 - s0);
}

// ---------------- gather quantized + loss sum ------------------------------
__global__ void k_quant_loss(const float* __restrict__ z, const float* __restrict__ cb,
                             const float* __restrict__ idx_f, float* __restrict__ out0,
                             float* __restrict__ loss_sum) {
  __shared__ float red[4];
  const int t = blockIdx.x * blockDim.x + threadIdx.x;   // float4 index
  const int n = t >> 5;
  const int d4 = t & 31;
  const int k = (int)idx_f[n];
  const float4 q  = *(const float4*)(cb + k * DIM + d4 * 4);
  const float4 zv = *(const float4*)(z + ((size_t)t << 2));
  *(float4*)(out0 + ((size_t)t << 2)) = q;
  const float dx = q.x - zv.x, dy = q.y - zv.y, dz = q.z - zv.z, dw = q.w - zv.w;
  float s = dx * dx + dy * dy + dz * dz + dw * dw;
#pragma unroll
  for (int m = 32; m; m >>= 1) s += __shfl_xor(s, m, 64);
  const int lane = threadIdx.x & 63, wv = threadIdx.x >> 6;
  if (lane == 0) red[wv] = s;
  __syncthreads();
  if (threadIdx.x == 0) atomicAdd(loss_sum, red[0] + red[1] + red[2] + red[3]);
}

// ---------------- n = sum(new_ema_count) -----------------------------------
__global__ void k_reduce_n(const float* __restrict__ out5, float* __restrict__ ntot) {
  __shared__ float red[4];
  const int tid = threadIdx.x;
  float s = out5[tid] + out5[tid + 256] + out5[tid + 512] + out5[tid + 768];
#pragma unroll
  for (int m = 32; m; m >>= 1) s += __shfl_xor(s, m, 64);
  if ((tid & 63) == 0) red[tid >> 6] = s;
  __syncthreads();
  if (tid == 0) *ntot = red[0] + red[1] + red[2] + red[3];
}

// ---------------- new_codebook + losses ------------------------------------
__global__ void k_final(const float* __restrict__ out5, const float* __restrict__ out6,
                        const float* __restrict__ ntot_p, const float* __restrict__ loss_sum,
                        float* __restrict__ out4, float* __restrict__ out2,
                        float* __restrict__ out3) {
  const int i = blockIdx.x * blockDim.x + threadIdx.x;
  const float ntot = *ntot_p;
  const int k = i >> 7;
  const float w = (out5[k] + 1e-5f) / (ntot + KCB * 1e-5f) * ntot;
  out4[i] = out6[i] / w;
  if (i == 0) {
    const float lv = *loss_sum * (1.f / 8388608.f);
    *out2 = lv; *out3 = lv;
  }
}

extern "C" void kernel_launch(void* const* d_in, const int* in_sizes, int n_in,
                              void* d_out, int out_size, void* d_ws, size_t ws_size,
                              hipStream_t stream) {
  (void)in_sizes; (void)n_in; (void)out_size; (void)ws_size;
  const float* z   = (const float*)d_in[0];
  const float* cb  = (const float*)d_in[1];
  const float* emc = (const float*)d_in[2];
  const float* emw = (const float*)d_in[3];
  float* out = (float*)d_out;
  float* out0 = out;                    // quantized_st  [8388608]
  float* out1 = out + 8388608;          // idx_map (float)[65536]
  float* out2 = out + 8454144;          // commitment_loss [1]
  float* out3 = out + 8454145;          // codebook_loss   [1]
  float* out4 = out + 8454146;          // new_codebook  [131072]
  float* out5 = out + 8585218;          // new_ema_count [1024]
  float* out6 = out + 8586242;          // new_ema_weight[131072]
  float* ws = (float*)d_ws;
  uint4* cbt      = (uint4*)ws;         // [16384] uint4 = 256KB (16B aligned)
  int* order      = (int*)(ws + 65536); // [65536]
  int* cand1      = (int*)(ws + 131072);// [65536]
  int* cand2      = (int*)(ws + 196608);// [65536]
  float* cc       = ws + 262144;        // [1024]
  int* hist       = (int*)(ws + 263168);// [1024]
  int* seg        = (int*)(ws + 264192);// [1025]
  int* cursor     = (int*)(ws + 265220);// [1024]
  float* loss_sum = ws + 266244;        // [1]
  float* ntot     = ws + 266245;        // [1]
  float* z_t = out0;                    // scratch: overwritten by k_quant_loss later

  hipMemsetAsync(hist, 0, KCB * sizeof(int), stream);
  hipLaunchKernelGGL(k_cbt, dim3(64), dim3(256), 0, stream, cb, cbt);
  hipLaunchKernelGGL(k_cc, dim3(4), dim3(256), 0, stream, cb, cc, loss_sum);
  hipLaunchKernelGGL(k_transpose, dim3(16, 2, 64), dim3(256), 0, stream, z, z_t);
  hipLaunchKernelGGL(k_mfma_argmin, dim3(NVEC / 128), dim3(256), 0, stream,
                     z, cbt, cc, cand1, cand2);
  hipLaunchKernelGGL(k_rescore, dim3(NVEC / 256), dim3(256), 0, stream,
                     z, cb, cc, cand1, cand2, out1);
  hipLaunchKernelGGL(k_hist, dim3(64), dim3(256), 0, stream, out1, hist);
  hipLaunchKernelGGL(k_scan, dim3(1), dim3(1024), 0, stream, hist, seg, cursor);
  hipLaunchKernelGGL(k_scatter, dim3(NVEC / 256), dim3(256), 0, stream, out1, cursor, order);
  hipLaunchKernelGGL(k_segreduce, dim3(KCB), dim3(128), 0, stream, z_t, seg, order,
                     emc, emw, out5, out6);
  hipLaunchKernelGGL(k_quant_loss, dim3(8192), dim3(256), 0, stream, z, cb, out1, out0, loss_sum);
  hipLaunchKernelGGL(k_reduce_n, dim3(1), dim3(256), 0, stream, out5, ntot);
  hipLaunchKernelGGL(k_final, dim3(512), dim3(256), 0, stream, out5, out6, ntot, loss_sum,
                     out4, out2, out3);
}

// Round 4
// 259.444 us; speedup vs baseline: 8.4579x; 1.8447x over previous
//
#include <hip/hip_runtime.h>

#define NVEC 65536   // B*H*W = 64*32*32
#define KCB  1024
#define DIM  128
#define HW   1024    // H*W
#define CHUNK 64

typedef __bf16 b16;
typedef b16 b16x8 __attribute__((ext_vector_type(8)));
typedef float f32x16 __attribute__((ext_vector_type(16)));

static __device__ __forceinline__ unsigned short f2bf(float f) {
  unsigned int x = __float_as_uint(f);
  unsigned int r = x + 0x7fffu + ((x >> 16) & 1u);   // RNE
  return (unsigned short)(r >> 16);
}

// ---------------- cc[k] = ||codebook[k]||^2 ; also zero loss accumulator ----
__global__ void k_cc(const float* __restrict__ cb, float* __restrict__ cc,
                     float* __restrict__ loss_sum) {
  const int k = blockIdx.x * blockDim.x + threadIdx.x;
  if (k == 0) *loss_sum = 0.f;
  if (k < KCB) {
    const float4* row = (const float4*)(cb + k * DIM);
    float s = 0.f;
#pragma unroll 8
    for (int j = 0; j < DIM / 4; ++j) {
      const float4 v = row[j];
      s = fmaf(v.x, v.x, s); s = fmaf(v.y, v.y, s);
      s = fmaf(v.z, v.z, s); s = fmaf(v.w, v.w, s);
    }
    cc[k] = s;
  }
}

// ---------------- cb -> cb_t bf16 packed [kc][dchunk][code7] 16B units -----
__global__ void k_cbt(const float* __restrict__ cb, uint4* __restrict__ cbt) {
  const int t = blockIdx.x * blockDim.x + threadIdx.x;   // 16384
  const int kc = t >> 11, u = t & 2047;
  const int code7 = u & 127, dch = u >> 7;
  const float* src = cb + (kc * 128 + code7) * 128 + dch * 8;
  const float4 x = *(const float4*)src;
  const float4 y = *(const float4*)(src + 4);
  uint4 o;
  o.x = (unsigned)f2bf(x.x) | ((unsigned)f2bf(x.y) << 16);
  o.y = (unsigned)f2bf(x.z) | ((unsigned)f2bf(x.w) << 16);
  o.z = (unsigned)f2bf(y.x) | ((unsigned)f2bf(y.y) << 16);
  o.w = (unsigned)f2bf(y.z) | ((unsigned)f2bf(y.w) << 16);
  cbt[t] = o;
}

// ---------------- transpose z[b][d][hw] -> z_t[(b*1024+hw)][d] (f32) -------
__global__ void k_transpose(const float* __restrict__ z, float* __restrict__ z_t) {
  __shared__ float tile[64][65];
  const int t = threadIdx.x;
  const int b = blockIdx.z;
  const int d0 = blockIdx.y * 64;
  const int hw0 = blockIdx.x * 64;
  const float* src = z + (size_t)b * 131072 + d0 * 1024 + hw0;
  {
    const int hw4 = (t & 15) * 4;
    const int dr = t >> 4;
#pragma unroll
    for (int j = 0; j < 4; ++j) {
      const int d = dr + 16 * j;
      const float4 v = *(const float4*)(src + d * 1024 + hw4);
      tile[d][hw4 + 0] = v.x; tile[d][hw4 + 1] = v.y;
      tile[d][hw4 + 2] = v.z; tile[d][hw4 + 3] = v.w;
    }
  }
  __syncthreads();
  float* dst = z_t + (size_t)b * 131072 + hw0 * 128 + d0;
  {
    const int d4 = (t & 31) * 4;
    const int hwr = t >> 5;
#pragma unroll
    for (int j = 0; j < 8; ++j) {
      const int hw = hwr + 8 * j;
      float4 v;
      v.x = tile[d4 + 0][hw]; v.y = tile[d4 + 1][hw];
      v.z = tile[d4 + 2][hw]; v.w = tile[d4 + 3][hw];
      *(float4*)(dst + hw * 128 + d4) = v;
    }
  }
}

// ---------------- MFMA argmin: top-2 candidates per row --------------------
__global__ __launch_bounds__(256, 2) void k_mfma_argmin(
    const float* __restrict__ z, const uint4* __restrict__ cbt,
    const float* __restrict__ cc, int* __restrict__ cand1,
    int* __restrict__ cand2) {
  __shared__ uint4 Bs[2048];                       // 32 KiB: u = dchunk*128 + code7
  const int tid = threadIdx.x;
  const int l = tid & 63, wv = tid >> 6;
  const int g = l >> 5;                            // k-group
  const int lm = l & 31;                           // row / code lane
  const int n0 = blockIdx.x * 128;
  const int b = n0 >> 10;
  const int hw = (n0 & (HW - 1)) + wv * 32 + lm;   // this lane's row (128 | 1024)
  const float* zp = z + (size_t)b * 131072 + hw;

  uint4 afrag[8];
#pragma unroll
  for (int ks = 0; ks < 8; ++ks) {
    const int d0 = ks * 16 + g * 8;
    unsigned u0 = (unsigned)f2bf(zp[(d0 + 0) * 1024]) | ((unsigned)f2bf(zp[(d0 + 1) * 1024]) << 16);
    unsigned u1 = (unsigned)f2bf(zp[(d0 + 2) * 1024]) | ((unsigned)f2bf(zp[(d0 + 3) * 1024]) << 16);
    unsigned u2 = (unsigned)f2bf(zp[(d0 + 4) * 1024]) | ((unsigned)f2bf(zp[(d0 + 5) * 1024]) << 16);
    unsigned u3 = (unsigned)f2bf(zp[(d0 + 6) * 1024]) | ((unsigned)f2bf(zp[(d0 + 7) * 1024]) << 16);
    afrag[ks] = make_uint4(u0, u1, u2, u3);
  }

  float b1[16], b2[16];
  int i1[16], i2[16];
#pragma unroll
  for (int r = 0; r < 16; ++r) { b1[r] = 1e30f; b2[r] = 1e30f; i1[r] = 0; i2[r] = 1; }

  for (int kc = 0; kc < 8; ++kc) {
    __syncthreads();                               // Bs readers of prev chunk done
#pragma unroll
    for (int i = 0; i < 8; ++i) {
      __builtin_amdgcn_global_load_lds(&cbt[kc * 2048 + wv * 512 + i * 64 + l],
                                       &Bs[wv * 512 + i * 64], 16, 0, 0);
    }
    float ccv[4];
#pragma unroll
    for (int f = 0; f < 4; ++f) ccv[f] = cc[kc * 128 + f * 32 + lm];
    __syncthreads();                               // all staging landed

    f32x16 acc[4] = {};
#pragma unroll
    for (int ks = 0; ks < 8; ++ks) {
      const b16x8 av = *reinterpret_cast<const b16x8*>(&afrag[ks]);
#pragma unroll
      for (int f = 0; f < 4; ++f) {
        const b16x8 bv = *reinterpret_cast<const b16x8*>(&Bs[(ks * 2 + g) * 128 + f * 32 + lm]);
        acc[f] = __builtin_amdgcn_mfma_f32_32x32x16_bf16(av, bv, acc[f], 0, 0, 0);
      }
    }
#pragma unroll
    for (int f = 0; f < 4; ++f) {
      const int c = kc * 128 + f * 32 + lm;
#pragma unroll
      for (int r = 0; r < 16; ++r) {
        const float s = fmaf(-2.f, acc[f][r], ccv[f]);
        const bool lt1 = s < b1[r];
        const bool lt2 = s < b2[r];
        b2[r] = lt1 ? b1[r] : (lt2 ? s : b2[r]);
        i2[r] = lt1 ? i1[r] : (lt2 ? c : i2[r]);
        b1[r] = lt1 ? s : b1[r];
        i1[r] = lt1 ? c : i1[r];
      }
    }
  }

#pragma unroll
  for (int r = 0; r < 16; ++r) {
    float a1 = b1[r], a2 = b2[r];
    int j1 = i1[r], j2 = i2[r];
#pragma unroll
    for (int m = 1; m < 32; m <<= 1) {
      const float o1 = __shfl_xor(a1, m, 64);
      const int oj1 = __shfl_xor(j1, m, 64);
      const float o2 = __shfl_xor(a2, m, 64);
      const int oj2 = __shfl_xor(j2, m, 64);
      const bool sw = (o1 < a1) || (o1 == a1 && oj1 < j1);
      const float w1 = sw ? o1 : a1; const int wj1 = sw ? oj1 : j1;
      float l1 = sw ? a1 : o1; int lj1 = sw ? j1 : oj1;
      if (a2 < l1 || (a2 == l1 && j2 < lj1)) { l1 = a2; lj1 = j2; }
      if (o2 < l1 || (o2 == l1 && oj2 < lj1)) { l1 = o2; lj1 = oj2; }
      a1 = w1; j1 = wj1; a2 = l1; j2 = lj1;
    }
    if (lm == 0) {
      const int rowg = n0 + wv * 32 + (r & 3) + 8 * (r >> 2) + 4 * g;
      cand1[rowg] = j1;
      cand2[rowg] = j2;
    }
  }
}

// ---------------- exact f32 rescore of the two candidates ------------------
__global__ void k_rescore(const float* __restrict__ z, const float* __restrict__ cb,
                          const float* __restrict__ ccw, const int* __restrict__ cand1,
                          const int* __restrict__ cand2, float* __restrict__ out1) {
  const int n = blockIdx.x * blockDim.x + threadIdx.x;
  const int b = n >> 10, hw = n & (HW - 1);
  const int k1 = cand1[n], k2 = cand2[n];
  const float* zp = z + (size_t)b * 131072 + hw;
  const float* c1 = cb + k1 * DIM;
  const float* c2 = cb + k2 * DIM;
  float d1 = 0.f, d2 = 0.f;
#pragma unroll 8
  for (int d = 0; d < DIM; ++d) {
    const float zv = zp[d * 1024];
    d1 = fmaf(zv, c1[d], d1);
    d2 = fmaf(zv, c2[d], d2);
  }
  const float s1 = fmaf(-2.f, d1, ccw[k1]);
  const float s2 = fmaf(-2.f, d2, ccw[k2]);
  const int kw = (s2 < s1 || (s2 == s1 && k2 < k1)) ? k2 : k1;
  out1[n] = (float)kw;
}

// ---------------- histogram of indices (LDS-aggregated) --------------------
__global__ void k_hist(const float* __restrict__ idx_f, int* __restrict__ hist) {
  __shared__ int h[KCB];
  const int t = threadIdx.x;
#pragma unroll
  for (int j = 0; j < 4; ++j) h[t + 256 * j] = 0;
  __syncthreads();
  const int n0 = blockIdx.x * 1024;
#pragma unroll
  for (int j = 0; j < 4; ++j) {
    const int k = (int)idx_f[n0 + t + 256 * j];
    atomicAdd(&h[k], 1);
  }
  __syncthreads();
#pragma unroll
  for (int j = 0; j < 4; ++j) {
    const int v = h[t + 256 * j];
    if (v) atomicAdd(&hist[t + 256 * j], v);
  }
}

// ---- exclusive scan over 1024 bins + out5 + ntot (single block) -----------
__global__ void k_scan(const int* __restrict__ hist, const float* __restrict__ emc,
                       int* __restrict__ seg, int* __restrict__ cursor,
                       float* __restrict__ out5, float* __restrict__ ntot) {
  __shared__ int tmp[KCB];
  __shared__ float red[16];
  const int t = threadIdx.x;
  const int v = hist[t];
  tmp[t] = v;
  __syncthreads();
  for (int off = 1; off < KCB; off <<= 1) {
    int x = 0;
    if (t >= off) x = tmp[t - off];
    __syncthreads();
    if (t >= off) tmp[t] += x;
    __syncthreads();
  }
  const int incl = tmp[t];
  seg[t] = incl - v;
  cursor[t] = incl - v;
  if (t == KCB - 1) seg[KCB] = incl;
  float o5 = 0.99f * emc[t] + 0.01f * (float)v;
  out5[t] = o5;
#pragma unroll
  for (int m = 32; m; m >>= 1) o5 += __shfl_xor(o5, m, 64);
  if ((t & 63) == 0) red[t >> 6] = o5;
  __syncthreads();
  if (t == 0) {
    float s = 0.f;
#pragma unroll
    for (int j = 0; j < 16; ++j) s += red[j];
    *ntot = s;
  }
}

// ---------------- scatter n's into per-code segments (+ key) ---------------
__global__ void k_scatter(const float* __restrict__ idx_f, int* __restrict__ cursor,
                          int* __restrict__ order, int* __restrict__ key) {
  const int n = blockIdx.x * blockDim.x + threadIdx.x;
  const int k = (int)idx_f[n];
  const int pos = atomicAdd(&cursor[k], 1);
  order[pos] = n;
  key[pos] = k;
}

// ---------------- out6 = 0.99 * emw ----------------------------------------
__global__ void k_init_w(const float* __restrict__ emw, float* __restrict__ out6) {
  const int i = blockIdx.x * blockDim.x + threadIdx.x;
  out6[i] = 0.99f * emw[i];
}

// ------- chunk-parallel segmented reduction: dw -> out6 (+= 0.01*sum) ------
// order[] sorted by key; block = one 64-row chunk, thread = dim.
__global__ __launch_bounds__(128) void k_chunkreduce(
    const float* __restrict__ z_t, const int* __restrict__ order,
    const int* __restrict__ key, float* __restrict__ out6) {
  __shared__ int so[CHUNK], sk[CHUNK];
  const int t = threadIdx.x;
  const int base = blockIdx.x * CHUNK;
  if (t < CHUNK) { so[t] = order[base + t]; sk[t] = key[base + t]; }
  __syncthreads();
  int kprev = sk[0];
  float acc = 0.f;
  int i = 0;
  while (i < CHUNK) {
    if (i + 8 <= CHUNK && sk[i] == kprev && sk[i + 7] == kprev) {
      // keys non-decreasing: ends equal => whole run equal. 8 loads in flight.
      const float v0 = z_t[(size_t)so[i + 0] * 128 + t];
      const float v1 = z_t[(size_t)so[i + 1] * 128 + t];
      const float v2 = z_t[(size_t)so[i + 2] * 128 + t];
      const float v3 = z_t[(size_t)so[i + 3] * 128 + t];
      const float v4 = z_t[(size_t)so[i + 4] * 128 + t];
      const float v5 = z_t[(size_t)so[i + 5] * 128 + t];
      const float v6 = z_t[(size_t)so[i + 6] * 128 + t];
      const float v7 = z_t[(size_t)so[i + 7] * 128 + t];
      acc += ((v0 + v1) + (v2 + v3)) + ((v4 + v5) + (v6 + v7));
      i += 8;
    } else {
      const int kk = sk[i];
      if (kk != kprev) {
        atomicAdd(&out6[kprev * 128 + t], 0.01f * acc);
        acc = 0.f; kprev = kk;
      }
      acc += z_t[(size_t)so[i] * 128 + t];
      ++i;
    }
  }
  atomicAdd(&out6[kprev * 128 + t], 0.01f * acc);
}

// ---------------- gather quantized + loss sum ------------------------------
__global__ void k_quant_loss(const float* __restrict__ z, const float* __restrict__ cb,
                             const float* __restrict__ idx_f, float* __restrict__ out0,
                             float* __restrict__ loss_sum) {
  __shared__ float red[4];
  const int t = blockIdx.x * blockDim.x + threadIdx.x;   // float4 index
  const int n = t >> 5;
  const int d4 = t & 31;
  const int k = (int)idx_f[n];
  const float4 q  = *(const float4*)(cb + k * DIM + d4 * 4);
  const float4 zv = *(const float4*)(z + ((size_t)t << 2));
  *(float4*)(out0 + ((size_t)t << 2)) = q;
  const float dx = q.x - zv.x, dy = q.y - zv.y, dz = q.z - zv.z, dw = q.w - zv.w;
  float s = dx * dx + dy * dy + dz * dz + dw * dw;
#pragma unroll
  for (int m = 32; m; m >>= 1) s += __shfl_xor(s, m, 64);
  const int lane = threadIdx.x & 63, wv = threadIdx.x >> 6;
  if (lane == 0) red[wv] = s;
  __syncthreads();
  if (threadIdx.x == 0) atomicAdd(loss_sum, red[0] + red[1] + red[2] + red[3]);
}

// ---------------- new_codebook + losses ------------------------------------
__global__ void k_final(const float* __restrict__ out5, const float* __restrict__ out6,
                        const float* __restrict__ ntot_p, const float* __restrict__ loss_sum,
                        float* __restrict__ out4, float* __restrict__ out2,
                        float* __restrict__ out3) {
  const int i = blockIdx.x * blockDim.x + threadIdx.x;
  const float ntot = *ntot_p;
  const int k = i >> 7;
  const float w = (out5[k] + 1e-5f) / (ntot + KCB * 1e-5f) * ntot;
  out4[i] = out6[i] / w;
  if (i == 0) {
    const float lv = *loss_sum * (1.f / 8388608.f);
    *out2 = lv; *out3 = lv;
  }
}

extern "C" void kernel_launch(void* const* d_in, const int* in_sizes, int n_in,
                              void* d_out, int out_size, void* d_ws, size_t ws_size,
                              hipStream_t stream) {
  (void)in_sizes; (void)n_in; (void)out_size; (void)ws_size;
  const float* z   = (const float*)d_in[0];
  const float* cb  = (const float*)d_in[1];
  const float* emc = (const float*)d_in[2];
  const float* emw = (const float*)d_in[3];
  float* out = (float*)d_out;
  float* out0 = out;                    // quantized_st  [8388608]
  float* out1 = out + 8388608;          // idx_map (float)[65536]
  float* out2 = out + 8454144;          // commitment_loss [1]
  float* out3 = out + 8454145;          // codebook_loss   [1]
  float* out4 = out + 8454146;          // new_codebook  [131072]
  float* out5 = out + 8585218;          // new_ema_count [1024]
  float* out6 = out + 8586242;          // new_ema_weight[131072]
  float* ws = (float*)d_ws;
  uint4* cbt      = (uint4*)ws;         // [16384] uint4 = 256KB
  int* order      = (int*)(ws + 65536); // [65536]
  int* key        = (int*)(ws + 131072);// [65536]
  int* cand1      = (int*)(ws + 196608);// [65536]
  int* cand2      = (int*)(ws + 262144);// [65536]
  float* cc       = ws + 327680;        // [1024]
  int* hist       = (int*)(ws + 328704);// [1024]
  int* seg        = (int*)(ws + 329728);// [1025]
  int* cursor     = (int*)(ws + 330756);// [1024]
  float* loss_sum = ws + 331780;        // [1]
  float* ntot     = ws + 331781;        // [1]
  float* z_t = out0;                    // scratch: overwritten by k_quant_loss later

  hipMemsetAsync(hist, 0, KCB * sizeof(int), stream);
  hipLaunchKernelGGL(k_cbt, dim3(64), dim3(256), 0, stream, cb, cbt);
  hipLaunchKernelGGL(k_cc, dim3(4), dim3(256), 0, stream, cb, cc, loss_sum);
  hipLaunchKernelGGL(k_transpose, dim3(16, 2, 64), dim3(256), 0, stream, z, z_t);
  hipLaunchKernelGGL(k_init_w, dim3(512), dim3(256), 0, stream, emw, out6);
  hipLaunchKernelGGL(k_mfma_argmin, dim3(NVEC / 128), dim3(256), 0, stream,
                     z, cbt, cc, cand1, cand2);
  hipLaunchKernelGGL(k_rescore, dim3(NVEC / 256), dim3(256), 0, stream,
                     z, cb, cc, cand1, cand2, out1);
  hipLaunchKernelGGL(k_hist, dim3(64), dim3(256), 0, stream, out1, hist);
  hipLaunchKernelGGL(k_scan, dim3(1), dim3(1024), 0, stream, hist, emc, seg, cursor,
                     out5, ntot);
  hipLaunchKernelGGL(k_scatter, dim3(NVEC / 256), dim3(256), 0, stream, out1, cursor,
                     order, key);
  hipLaunchKernelGGL(k_chunkreduce, dim3(NVEC / CHUNK), dim3(128), 0, stream,
                     z_t, order, key, out6);
  hipLaunchKernelGGL(k_quant_loss, dim3(8192), dim3(256), 0, stream, z, cb, out1, out0, loss_sum);
  hipLaunchKernelGGL(k_final, dim3(512), dim3(256), 0, stream, out5, out6, ntot, loss_sum,
                     out4, out2, out3);
}

// Round 5
// 163.649 us; speedup vs baseline: 13.4089x; 1.5854x over previous
//
#include <hip/hip_runtime.h>

#define NVEC 65536   // B*H*W = 64*32*32
#define KCB  1024
#define DIM  128
#define HW   1024    // H*W
#define CHUNK 64
#define QLBLOCKS 2048

typedef __bf16 b16;
typedef b16 b16x8 __attribute__((ext_vector_type(8)));
typedef float f32x16 __attribute__((ext_vector_type(16)));

static __device__ __forceinline__ unsigned short f2bf(float f) {
  unsigned int x = __float_as_uint(f);
  unsigned int r = x + 0x7fffu + ((x >> 16) & 1u);   // RNE
  return (unsigned short)(r >> 16);
}

// ---------------- cc[k] = ||codebook[k]||^2 --------------------------------
__global__ void k_cc(const float* __restrict__ cb, float* __restrict__ cc) {
  const int k = blockIdx.x * blockDim.x + threadIdx.x;
  if (k < KCB) {
    const float4* row = (const float4*)(cb + k * DIM);
    float s = 0.f;
#pragma unroll 8
    for (int j = 0; j < DIM / 4; ++j) {
      const float4 v = row[j];
      s = fmaf(v.x, v.x, s); s = fmaf(v.y, v.y, s);
      s = fmaf(v.z, v.z, s); s = fmaf(v.w, v.w, s);
    }
    cc[k] = s;
  }
}

// ---------------- cb -> cb_t bf16 packed [kc][dchunk][code7] 16B units -----
__global__ void k_cbt(const float* __restrict__ cb, uint4* __restrict__ cbt) {
  const int t = blockIdx.x * blockDim.x + threadIdx.x;   // 16384
  const int kc = t >> 11, u = t & 2047;
  const int code7 = u & 127, dch = u >> 7;
  const float* src = cb + (kc * 128 + code7) * 128 + dch * 8;
  const float4 x = *(const float4*)src;
  const float4 y = *(const float4*)(src + 4);
  uint4 o;
  o.x = (unsigned)f2bf(x.x) | ((unsigned)f2bf(x.y) << 16);
  o.y = (unsigned)f2bf(x.z) | ((unsigned)f2bf(x.w) << 16);
  o.z = (unsigned)f2bf(y.x) | ((unsigned)f2bf(y.y) << 16);
  o.w = (unsigned)f2bf(y.z) | ((unsigned)f2bf(y.w) << 16);
  cbt[t] = o;
}

// ---------------- transpose z[b][d][hw] -> z_t[(b*1024+hw)][d] (f32) -------
__global__ void k_transpose(const float* __restrict__ z, float* __restrict__ z_t) {
  __shared__ float tile[64][65];
  const int t = threadIdx.x;
  const int b = blockIdx.z;
  const int d0 = blockIdx.y * 64;
  const int hw0 = blockIdx.x * 64;
  const float* src = z + (size_t)b * 131072 + d0 * 1024 + hw0;
  {
    const int hw4 = (t & 15) * 4;
    const int dr = t >> 4;
#pragma unroll
    for (int j = 0; j < 4; ++j) {
      const int d = dr + 16 * j;
      const float4 v = *(const float4*)(src + d * 1024 + hw4);
      tile[d][hw4 + 0] = v.x; tile[d][hw4 + 1] = v.y;
      tile[d][hw4 + 2] = v.z; tile[d][hw4 + 3] = v.w;
    }
  }
  __syncthreads();
  float* dst = z_t + (size_t)b * 131072 + hw0 * 128 + d0;
  {
    const int d4 = (t & 31) * 4;
    const int hwr = t >> 5;
#pragma unroll
    for (int j = 0; j < 8; ++j) {
      const int hw = hwr + 8 * j;
      float4 v;
      v.x = tile[d4 + 0][hw]; v.y = tile[d4 + 1][hw];
      v.z = tile[d4 + 2][hw]; v.w = tile[d4 + 3][hw];
      *(float4*)(dst + hw * 128 + d4) = v;
    }
  }
}

// ---------------- MFMA argmin: top-2 candidates per row --------------------
__global__ __launch_bounds__(256, 2) void k_mfma_argmin(
    const float* __restrict__ z, const uint4* __restrict__ cbt,
    const float* __restrict__ cc, int* __restrict__ cand1,
    int* __restrict__ cand2) {
  __shared__ uint4 Bs[2048];                       // 32 KiB: u = dchunk*128 + code7
  const int tid = threadIdx.x;
  const int l = tid & 63, wv = tid >> 6;
  const int g = l >> 5;                            // k-group
  const int lm = l & 31;                           // row / code lane
  const int n0 = blockIdx.x * 128;
  const int b = n0 >> 10;
  const int hw = (n0 & (HW - 1)) + wv * 32 + lm;   // this lane's row (128 | 1024)
  const float* zp = z + (size_t)b * 131072 + hw;

  uint4 afrag[8];
#pragma unroll
  for (int ks = 0; ks < 8; ++ks) {
    const int d0 = ks * 16 + g * 8;
    unsigned u0 = (unsigned)f2bf(zp[(d0 + 0) * 1024]) | ((unsigned)f2bf(zp[(d0 + 1) * 1024]) << 16);
    unsigned u1 = (unsigned)f2bf(zp[(d0 + 2) * 1024]) | ((unsigned)f2bf(zp[(d0 + 3) * 1024]) << 16);
    unsigned u2 = (unsigned)f2bf(zp[(d0 + 4) * 1024]) | ((unsigned)f2bf(zp[(d0 + 5) * 1024]) << 16);
    unsigned u3 = (unsigned)f2bf(zp[(d0 + 6) * 1024]) | ((unsigned)f2bf(zp[(d0 + 7) * 1024]) << 16);
    afrag[ks] = make_uint4(u0, u1, u2, u3);
  }

  float b1[16], b2[16];
  int i1[16], i2[16];
#pragma unroll
  for (int r = 0; r < 16; ++r) { b1[r] = 1e30f; b2[r] = 1e30f; i1[r] = 0; i2[r] = 1; }

  for (int kc = 0; kc < 8; ++kc) {
    __syncthreads();                               // Bs readers of prev chunk done
#pragma unroll
    for (int i = 0; i < 8; ++i) {
      __builtin_amdgcn_global_load_lds(&cbt[kc * 2048 + wv * 512 + i * 64 + l],
                                       &Bs[wv * 512 + i * 64], 16, 0, 0);
    }
    float ccv[4];
#pragma unroll
    for (int f = 0; f < 4; ++f) ccv[f] = cc[kc * 128 + f * 32 + lm];
    __syncthreads();                               // all staging landed

    f32x16 acc[4] = {};
#pragma unroll
    for (int ks = 0; ks < 8; ++ks) {
      const b16x8 av = *reinterpret_cast<const b16x8*>(&afrag[ks]);
#pragma unroll
      for (int f = 0; f < 4; ++f) {
        const b16x8 bv = *reinterpret_cast<const b16x8*>(&Bs[(ks * 2 + g) * 128 + f * 32 + lm]);
        acc[f] = __builtin_amdgcn_mfma_f32_32x32x16_bf16(av, bv, acc[f], 0, 0, 0);
      }
    }
#pragma unroll
    for (int f = 0; f < 4; ++f) {
      const int c = kc * 128 + f * 32 + lm;
#pragma unroll
      for (int r = 0; r < 16; ++r) {
        const float s = fmaf(-2.f, acc[f][r], ccv[f]);
        const bool lt1 = s < b1[r];
        const bool lt2 = s < b2[r];
        b2[r] = lt1 ? b1[r] : (lt2 ? s : b2[r]);
        i2[r] = lt1 ? i1[r] : (lt2 ? c : i2[r]);
        b1[r] = lt1 ? s : b1[r];
        i1[r] = lt1 ? c : i1[r];
      }
    }
  }

#pragma unroll
  for (int r = 0; r < 16; ++r) {
    float a1 = b1[r], a2 = b2[r];
    int j1 = i1[r], j2 = i2[r];
#pragma unroll
    for (int m = 1; m < 32; m <<= 1) {
      const float o1 = __shfl_xor(a1, m, 64);
      const int oj1 = __shfl_xor(j1, m, 64);
      const float o2 = __shfl_xor(a2, m, 64);
      const int oj2 = __shfl_xor(j2, m, 64);
      const bool sw = (o1 < a1) || (o1 == a1 && oj1 < j1);
      const float w1 = sw ? o1 : a1; const int wj1 = sw ? oj1 : j1;
      float l1 = sw ? a1 : o1; int lj1 = sw ? j1 : oj1;
      if (a2 < l1 || (a2 == l1 && j2 < lj1)) { l1 = a2; lj1 = j2; }
      if (o2 < l1 || (o2 == l1 && oj2 < lj1)) { l1 = o2; lj1 = oj2; }
      a1 = w1; j1 = wj1; a2 = l1; j2 = lj1;
    }
    if (lm == 0) {
      const int rowg = n0 + wv * 32 + (r & 3) + 8 * (r >> 2) + 4 * g;
      cand1[rowg] = j1;
      cand2[rowg] = j2;
    }
  }
}

// ---------------- exact f32 rescore of the two candidates ------------------
__global__ void k_rescore(const float* __restrict__ z, const float* __restrict__ cb,
                          const float* __restrict__ ccw, const int* __restrict__ cand1,
                          const int* __restrict__ cand2, float* __restrict__ out1) {
  const int n = blockIdx.x * blockDim.x + threadIdx.x;
  const int b = n >> 10, hw = n & (HW - 1);
  const int k1 = cand1[n], k2 = cand2[n];
  const float* zp = z + (size_t)b * 131072 + hw;
  const float* c1 = cb + k1 * DIM;
  const float* c2 = cb + k2 * DIM;
  float d1 = 0.f, d2 = 0.f;
#pragma unroll 8
  for (int d = 0; d < DIM; ++d) {
    const float zv = zp[d * 1024];
    d1 = fmaf(zv, c1[d], d1);
    d2 = fmaf(zv, c2[d], d2);
  }
  const float s1 = fmaf(-2.f, d1, ccw[k1]);
  const float s2 = fmaf(-2.f, d2, ccw[k2]);
  const int kw = (s2 < s1 || (s2 == s1 && k2 < k1)) ? k2 : k1;
  out1[n] = (float)kw;
}

// ---------------- histogram of indices (LDS-aggregated) --------------------
__global__ void k_hist(const float* __restrict__ idx_f, int* __restrict__ hist) {
  __shared__ int h[KCB];
  const int t = threadIdx.x;
#pragma unroll
  for (int j = 0; j < 4; ++j) h[t + 256 * j] = 0;
  __syncthreads();
  const int n0 = blockIdx.x * 1024;
#pragma unroll
  for (int j = 0; j < 4; ++j) {
    const int k = (int)idx_f[n0 + t + 256 * j];
    atomicAdd(&h[k], 1);
  }
  __syncthreads();
#pragma unroll
  for (int j = 0; j < 4; ++j) {
    const int v = h[t + 256 * j];
    if (v) atomicAdd(&hist[t + 256 * j], v);
  }
}

// ---- exclusive scan over 1024 bins + out5 + ntot (single block) -----------
__global__ void k_scan(const int* __restrict__ hist, const float* __restrict__ emc,
                       int* __restrict__ seg, int* __restrict__ cursor,
                       float* __restrict__ out5, float* __restrict__ ntot) {
  __shared__ int tmp[KCB];
  __shared__ float red[16];
  const int t = threadIdx.x;
  const int v = hist[t];
  tmp[t] = v;
  __syncthreads();
  for (int off = 1; off < KCB; off <<= 1) {
    int x = 0;
    if (t >= off) x = tmp[t - off];
    __syncthreads();
    if (t >= off) tmp[t] += x;
    __syncthreads();
  }
  const int incl = tmp[t];
  seg[t] = incl - v;
  cursor[t] = incl - v;
  if (t == KCB - 1) seg[KCB] = incl;
  float o5 = 0.99f * emc[t] + 0.01f * (float)v;
  out5[t] = o5;
#pragma unroll
  for (int m = 32; m; m >>= 1) o5 += __shfl_xor(o5, m, 64);
  if ((t & 63) == 0) red[t >> 6] = o5;
  __syncthreads();
  if (t == 0) {
    float s = 0.f;
#pragma unroll
    for (int j = 0; j < 16; ++j) s += red[j];
    *ntot = s;
  }
}

// ---------------- scatter n's into per-code segments (+ key) ---------------
__global__ void k_scatter(const float* __restrict__ idx_f, int* __restrict__ cursor,
                          int* __restrict__ order, int* __restrict__ key) {
  const int n = blockIdx.x * blockDim.x + threadIdx.x;
  const int k = (int)idx_f[n];
  const int pos = atomicAdd(&cursor[k], 1);
  order[pos] = n;
  key[pos] = k;
}

// ---------------- out6 = 0.99 * emw ----------------------------------------
__global__ void k_init_w(const float* __restrict__ emw, float* __restrict__ out6) {
  const int i = blockIdx.x * blockDim.x + threadIdx.x;
  out6[i] = 0.99f * emw[i];
}

// ------- chunk-parallel segmented reduction: dw -> out6 (+= 0.01*sum) ------
__global__ __launch_bounds__(128) void k_chunkreduce(
    const float* __restrict__ z_t, const int* __restrict__ order,
    const int* __restrict__ key, float* __restrict__ out6) {
  __shared__ int so[CHUNK], sk[CHUNK];
  const int t = threadIdx.x;
  const int base = blockIdx.x * CHUNK;
  if (t < CHUNK) { so[t] = order[base + t]; sk[t] = key[base + t]; }
  __syncthreads();
  int kprev = sk[0];
  float acc = 0.f;
  int i = 0;
  while (i < CHUNK) {
    if (i + 8 <= CHUNK && sk[i] == kprev && sk[i + 7] == kprev) {
      const float v0 = z_t[(size_t)so[i + 0] * 128 + t];
      const float v1 = z_t[(size_t)so[i + 1] * 128 + t];
      const float v2 = z_t[(size_t)so[i + 2] * 128 + t];
      const float v3 = z_t[(size_t)so[i + 3] * 128 + t];
      const float v4 = z_t[(size_t)so[i + 4] * 128 + t];
      const float v5 = z_t[(size_t)so[i + 5] * 128 + t];
      const float v6 = z_t[(size_t)so[i + 6] * 128 + t];
      const float v7 = z_t[(size_t)so[i + 7] * 128 + t];
      acc += ((v0 + v1) + (v2 + v3)) + ((v4 + v5) + (v6 + v7));
      i += 8;
    } else {
      const int kk = sk[i];
      if (kk != kprev) {
        atomicAdd(&out6[kprev * 128 + t], 0.01f * acc);
        acc = 0.f; kprev = kk;
      }
      acc += z_t[(size_t)so[i] * 128 + t];
      ++i;
    }
  }
  atomicAdd(&out6[kprev * 128 + t], 0.01f * acc);
}

// ------- gather quantized + per-block loss partial (no global atomics) -----
__global__ void k_quant_loss(const float* __restrict__ z, const float* __restrict__ cb,
                             const float* __restrict__ idx_f, float* __restrict__ out0,
                             float* __restrict__ partials) {
  __shared__ float red[4];
  float s = 0.f;
#pragma unroll
  for (int it = 0; it < 4; ++it) {
    const int t = blockIdx.x * 1024 + it * 256 + threadIdx.x;   // float4 index
    const int n = t >> 5;
    const int d4 = t & 31;
    const int k = (int)idx_f[n];
    const float4 q  = *(const float4*)(cb + k * DIM + d4 * 4);
    const float4 zv = *(const float4*)(z + ((size_t)t << 2));
    *(float4*)(out0 + ((size_t)t << 2)) = q;
    const float dx = q.x - zv.x, dy = q.y - zv.y, dz = q.z - zv.z, dw = q.w - zv.w;
    s += dx * dx + dy * dy + dz * dz + dw * dw;
  }
#pragma unroll
  for (int m = 32; m; m >>= 1) s += __shfl_xor(s, m, 64);
  const int lane = threadIdx.x & 63, wv = threadIdx.x >> 6;
  if (lane == 0) red[wv] = s;
  __syncthreads();
  if (threadIdx.x == 0) partials[blockIdx.x] = red[0] + red[1] + red[2] + red[3];
}

// ---------------- reduce loss partials -> loss_sum -------------------------
__global__ void k_losssum(const float* __restrict__ partials, float* __restrict__ loss_sum) {
  __shared__ float red[4];
  const int t = threadIdx.x;
  float s = 0.f;
#pragma unroll
  for (int j = 0; j < QLBLOCKS / 256; ++j) s += partials[t + 256 * j];
#pragma unroll
  for (int m = 32; m; m >>= 1) s += __shfl_xor(s, m, 64);
  if ((t & 63) == 0) red[t >> 6] = s;
  __syncthreads();
  if (t == 0) *loss_sum = red[0] + red[1] + red[2] + red[3];
}

// ---------------- new_codebook + losses ------------------------------------
__global__ void k_final(const float* __restrict__ out5, const float* __restrict__ out6,
                        const float* __restrict__ ntot_p, const float* __restrict__ loss_sum,
                        float* __restrict__ out4, float* __restrict__ out2,
                        float* __restrict__ out3) {
  const int i = blockIdx.x * blockDim.x + threadIdx.x;
  const float ntot = *ntot_p;
  const int k = i >> 7;
  const float w = (out5[k] + 1e-5f) / (ntot + KCB * 1e-5f) * ntot;
  out4[i] = out6[i] / w;
  if (i == 0) {
    const float lv = *loss_sum * (1.f / 8388608.f);
    *out2 = lv; *out3 = lv;
  }
}

extern "C" void kernel_launch(void* const* d_in, const int* in_sizes, int n_in,
                              void* d_out, int out_size, void* d_ws, size_t ws_size,
                              hipStream_t stream) {
  (void)in_sizes; (void)n_in; (void)out_size; (void)ws_size;
  const float* z   = (const float*)d_in[0];
  const float* cb  = (const float*)d_in[1];
  const float* emc = (const float*)d_in[2];
  const float* emw = (const float*)d_in[3];
  float* out = (float*)d_out;
  float* out0 = out;                    // quantized_st  [8388608]
  float* out1 = out + 8388608;          // idx_map (float)[65536]
  float* out2 = out + 8454144;          // commitment_loss [1]
  float* out3 = out + 8454145;          // codebook_loss   [1]
  float* out4 = out + 8454146;          // new_codebook  [131072]
  float* out5 = out + 8585218;          // new_ema_count [1024]
  float* out6 = out + 8586242;          // new_ema_weight[131072]
  float* ws = (float*)d_ws;
  uint4* cbt      = (uint4*)ws;         // [16384] uint4 = 256KB
  int* order      = (int*)(ws + 65536); // [65536]
  int* key        = (int*)(ws + 131072);// [65536]
  int* cand1      = (int*)(ws + 196608);// [65536]
  int* cand2      = (int*)(ws + 262144);// [65536]
  float* cc       = ws + 327680;        // [1024]
  int* hist       = (int*)(ws + 328704);// [1024]
  int* seg        = (int*)(ws + 329728);// [1025]
  int* cursor     = (int*)(ws + 330756);// [1024]
  float* loss_sum = ws + 331780;        // [1]
  float* ntot     = ws + 331781;        // [1]
  float* partials = ws + 331784;        // [2048]
  float* z_t = out0;                    // scratch: overwritten by k_quant_loss later

  hipMemsetAsync(hist, 0, KCB * sizeof(int), stream);
  hipLaunchKernelGGL(k_cbt, dim3(64), dim3(256), 0, stream, cb, cbt);
  hipLaunchKernelGGL(k_cc, dim3(4), dim3(256), 0, stream, cb, cc);
  hipLaunchKernelGGL(k_transpose, dim3(16, 2, 64), dim3(256), 0, stream, z, z_t);
  hipLaunchKernelGGL(k_init_w, dim3(512), dim3(256), 0, stream, emw, out6);
  hipLaunchKernelGGL(k_mfma_argmin, dim3(NVEC / 128), dim3(256), 0, stream,
                     z, cbt, cc, cand1, cand2);
  hipLaunchKernelGGL(k_rescore, dim3(NVEC / 256), dim3(256), 0, stream,
                     z, cb, cc, cand1, cand2, out1);
  hipLaunchKernelGGL(k_hist, dim3(64), dim3(256), 0, stream, out1, hist);
  hipLaunchKernelGGL(k_scan, dim3(1), dim3(1024), 0, stream, hist, emc, seg, cursor,
                     out5, ntot);
  hipLaunchKernelGGL(k_scatter, dim3(NVEC / 256), dim3(256), 0, stream, out1, cursor,
                     order, key);
  hipLaunchKernelGGL(k_chunkreduce, dim3(NVEC / CHUNK), dim3(128), 0, stream,
                     z_t, order, key, out6);
  hipLaunchKernelGGL(k_quant_loss, dim3(QLBLOCKS), dim3(256), 0, stream, z, cb, out1,
                     out0, partials);
  hipLaunchKernelGGL(k_losssum, dim3(1), dim3(256), 0, stream, partials, loss_sum);
  hipLaunchKernelGGL(k_final, dim3(512), dim3(256), 0, stream, out5, out6, ntot, loss_sum,
                     out4, out2, out3);
}

// Round 6
// 159.108 us; speedup vs baseline: 13.7916x; 1.0285x over previous
//
#include <hip/hip_runtime.h>

#define NVEC 65536   // B*H*W = 64*32*32
#define KCB  1024
#define DIM  128
#define HW   1024    // H*W
#define CHUNK 64
#define QLBLOCKS 2048

typedef __bf16 b16;
typedef b16 b16x8 __attribute__((ext_vector_type(8)));
typedef float f32x16 __attribute__((ext_vector_type(16)));

static __device__ __forceinline__ unsigned short f2bf(float f) {
  unsigned int x = __float_as_uint(f);
  unsigned int r = x + 0x7fffu + ((x >> 16) & 1u);   // RNE
  return (unsigned short)(r >> 16);
}

// ---- fused: cbt (bf16 pack [kc][dchunk][code7]) + cc[k]=||cb_k||^2 --------
__global__ void k_prep(const float* __restrict__ cb, uint4* __restrict__ cbt,
                       float* __restrict__ cc) {
  const int t = blockIdx.x * blockDim.x + threadIdx.x;   // 16384
  const int kc = t >> 11, u = t & 2047;
  const int code7 = u & 127, dch = u >> 7;
  const float* src = cb + (kc * 128 + code7) * 128 + dch * 8;
  const float4 x = *(const float4*)src;
  const float4 y = *(const float4*)(src + 4);
  uint4 o;
  o.x = (unsigned)f2bf(x.x) | ((unsigned)f2bf(x.y) << 16);
  o.y = (unsigned)f2bf(x.z) | ((unsigned)f2bf(x.w) << 16);
  o.z = (unsigned)f2bf(y.x) | ((unsigned)f2bf(y.y) << 16);
  o.w = (unsigned)f2bf(y.z) | ((unsigned)f2bf(y.w) << 16);
  cbt[t] = o;
  if (blockIdx.x < 4) {
    const int k = blockIdx.x * 256 + threadIdx.x;
    const float4* row = (const float4*)(cb + k * DIM);
    float s = 0.f;
#pragma unroll 8
    for (int j = 0; j < DIM / 4; ++j) {
      const float4 v = row[j];
      s = fmaf(v.x, v.x, s); s = fmaf(v.y, v.y, s);
      s = fmaf(v.z, v.z, s); s = fmaf(v.w, v.w, s);
    }
    cc[k] = s;
  }
}

// ---------------- out6 = 0.99 * emw ----------------------------------------
__global__ void k_init_w(const float* __restrict__ emw, float* __restrict__ out6) {
  const int i = blockIdx.x * blockDim.x + threadIdx.x;
  out6[i] = 0.99f * emw[i];
}

// ---- MFMA argmin v2: codes split across 2 blocks; packed(u32) top-2 -------
// bid: tile = bid>>1 (128 rows), half = bid&1 (512 codes). half==0 blocks
// also emit z_t (f32 transpose) from the A-fragment loads.
__global__ __launch_bounds__(256, 4) void k_argmin2(
    const float* __restrict__ z, const uint4* __restrict__ cbt,
    const float* __restrict__ cc, uint2* __restrict__ pcand,
    float* __restrict__ z_t) {
  __shared__ uint4 Bs[2048];                       // 32 KiB: u = dchunk*128 + code7
  const int tid = threadIdx.x;
  const int l = tid & 63, wv = tid >> 6;
  const int g = l >> 5;                            // k-slice group
  const int lm = l & 31;                           // row-lane / code-lane
  const int tile = blockIdx.x >> 1;
  const int half = blockIdx.x & 1;
  const int n0 = tile * 128;
  const int b = n0 >> 10;
  const int hw = (n0 & (HW - 1)) + wv * 32 + lm;   // spatial row (128 | 1024)
  const float* zp = z + (size_t)b * 131072 + hw;

  // A fragments (and z_t spill on half 0)
  uint4 afrag[8];
#pragma unroll
  for (int ks = 0; ks < 8; ++ks) {
    const int d0 = ks * 16 + g * 8;
    const float v0 = zp[(d0 + 0) * 1024], v1 = zp[(d0 + 1) * 1024];
    const float v2 = zp[(d0 + 2) * 1024], v3 = zp[(d0 + 3) * 1024];
    const float v4 = zp[(d0 + 4) * 1024], v5 = zp[(d0 + 5) * 1024];
    const float v6 = zp[(d0 + 6) * 1024], v7 = zp[(d0 + 7) * 1024];
    if (half == 0) {
      float* dst = z_t + ((size_t)(b * 1024 + hw)) * 128 + d0;
      *(float4*)dst = make_float4(v0, v1, v2, v3);
      *(float4*)(dst + 4) = make_float4(v4, v5, v6, v7);
    }
    afrag[ks].x = (unsigned)f2bf(v0) | ((unsigned)f2bf(v1) << 16);
    afrag[ks].y = (unsigned)f2bf(v2) | ((unsigned)f2bf(v3) << 16);
    afrag[ks].z = (unsigned)f2bf(v4) | ((unsigned)f2bf(v5) << 16);
    afrag[ks].w = (unsigned)f2bf(v6) | ((unsigned)f2bf(v7) << 16);
  }

  unsigned pm1[16], pm2[16];
#pragma unroll
  for (int r = 0; r < 16; ++r) { pm1[r] = 0xFFFFFFFFu; pm2[r] = 0xFFFFFFFFu; }

  const int kcbase = half * 4;
  for (int kc4 = 0; kc4 < 4; ++kc4) {
    const int kc = kcbase + kc4;
    __syncthreads();                               // Bs readers of prev chunk done
#pragma unroll
    for (int i = 0; i < 8; ++i) {
      __builtin_amdgcn_global_load_lds(&cbt[kc * 2048 + wv * 512 + i * 64 + l],
                                       &Bs[wv * 512 + i * 64], 16, 0, 0);
    }
    float ccv[4];
#pragma unroll
    for (int f = 0; f < 4; ++f) ccv[f] = cc[kc * 128 + f * 32 + lm];
    __syncthreads();                               // staging landed

#pragma unroll
    for (int fp = 0; fp < 4; fp += 2) {
      f32x16 a0 = {}, a1 = {};
#pragma unroll
      for (int ks = 0; ks < 8; ++ks) {
        const b16x8 av = *reinterpret_cast<const b16x8*>(&afrag[ks]);
        const b16x8 bv0 = *reinterpret_cast<const b16x8*>(&Bs[(ks * 2 + g) * 128 + fp * 32 + lm]);
        const b16x8 bv1 = *reinterpret_cast<const b16x8*>(&Bs[(ks * 2 + g) * 128 + (fp + 1) * 32 + lm]);
        a0 = __builtin_amdgcn_mfma_f32_32x32x16_bf16(av, bv0, a0, 0, 0, 0);
        a1 = __builtin_amdgcn_mfma_f32_32x32x16_bf16(av, bv1, a1, 0, 0, 0);
      }
      const unsigned c0 = (unsigned)(kc * 128 + fp * 32 + lm);
      const unsigned c1 = c0 + 32;
#pragma unroll
      for (int r = 0; r < 16; ++r) {
        {
          const float s = fmaf(-2.f, a0[r], ccv[fp]);
          const unsigned x = __float_as_uint(s);
          unsigned u = x ^ ((unsigned)((int)x >> 31) | 0x80000000u);
          u = (u & 0xFFFFFC00u) | c0;
          const unsigned t = pm1[r] > u ? pm1[r] : u;
          pm1[r] = pm1[r] < u ? pm1[r] : u;
          pm2[r] = pm2[r] < t ? pm2[r] : t;
        }
        {
          const float s = fmaf(-2.f, a1[r], ccv[fp + 1]);
          const unsigned x = __float_as_uint(s);
          unsigned u = x ^ ((unsigned)((int)x >> 31) | 0x80000000u);
          u = (u & 0xFFFFFC00u) | c1;
          const unsigned t = pm1[r] > u ? pm1[r] : u;
          pm1[r] = pm1[r] < u ? pm1[r] : u;
          pm2[r] = pm2[r] < t ? pm2[r] : t;
        }
      }
    }
  }

  // top-2 merge across the 32 code-lanes (butterfly stays within each half)
#pragma unroll
  for (int r = 0; r < 16; ++r) {
    unsigned u1 = pm1[r], u2 = pm2[r];
#pragma unroll
    for (int m = 1; m < 32; m <<= 1) {
      const unsigned o1 = (unsigned)__shfl_xor((int)u1, m, 64);
      const unsigned o2 = (unsigned)__shfl_xor((int)u2, m, 64);
      const unsigned t = u1 > o1 ? u1 : o1;
      u1 = u1 < o1 ? u1 : o1;
      const unsigned mn = u2 < o2 ? u2 : o2;
      u2 = mn < t ? mn : t;
    }
    if (lm == 0) {
      const int rowg = n0 + wv * 32 + (r & 3) + 8 * (r >> 2) + 4 * g;
      pcand[half * NVEC + rowg] = make_uint2(u1, u2);
    }
  }
}

// ---- merge 2x top-2, exact f32 rescore, emit idx + LDS histogram ----------
__global__ void k_rescore_hist(const float* __restrict__ z_t, const float* __restrict__ cb,
                               const float* __restrict__ ccw, const uint2* __restrict__ pcand,
                               float* __restrict__ out1, int* __restrict__ hist) {
  __shared__ int h[KCB];
  const int tid = threadIdx.x;
#pragma unroll
  for (int j = 0; j < 4; ++j) h[tid + 256 * j] = 0;
  __syncthreads();
  const int n = blockIdx.x * 256 + tid;
  const uint2 A = pcand[n];
  const uint2 Bq = pcand[NVEC + n];
  const unsigned t = A.x > Bq.x ? A.x : Bq.x;
  const unsigned w1 = A.x < Bq.x ? A.x : Bq.x;
  const unsigned mn2 = A.y < Bq.y ? A.y : Bq.y;
  const unsigned w2 = mn2 < t ? mn2 : t;
  const int k1 = (int)(w1 & 1023u);
  const int k2 = (int)(w2 & 1023u);
  const float* zr = z_t + (size_t)n * DIM;
  const float4* c1 = (const float4*)(cb + k1 * DIM);
  const float4* c2 = (const float4*)(cb + k2 * DIM);
  float d1 = 0.f, d2 = 0.f;
#pragma unroll 8
  for (int j = 0; j < DIM / 4; ++j) {
    const float4 zv = *(const float4*)(zr + j * 4);
    const float4 a = c1[j], bb = c2[j];
    d1 = fmaf(zv.x, a.x, d1); d1 = fmaf(zv.y, a.y, d1);
    d1 = fmaf(zv.z, a.z, d1); d1 = fmaf(zv.w, a.w, d1);
    d2 = fmaf(zv.x, bb.x, d2); d2 = fmaf(zv.y, bb.y, d2);
    d2 = fmaf(zv.z, bb.z, d2); d2 = fmaf(zv.w, bb.w, d2);
  }
  const float s1 = fmaf(-2.f, d1, ccw[k1]);
  const float s2 = fmaf(-2.f, d2, ccw[k2]);
  const int kw = (s2 < s1 || (s2 == s1 && k2 < k1)) ? k2 : k1;
  out1[n] = (float)kw;
  atomicAdd(&h[kw], 1);
  __syncthreads();
#pragma unroll
  for (int j = 0; j < 4; ++j) {
    const int v = h[tid + 256 * j];
    if (v) atomicAdd(&hist[tid + 256 * j], v);
  }
}

// ---- exclusive scan over 1024 bins + out5 + ntot (single block) -----------
__global__ void k_scan(const int* __restrict__ hist, const float* __restrict__ emc,
                       int* __restrict__ cursor, float* __restrict__ out5,
                       float* __restrict__ ntot) {
  __shared__ int tmp[KCB];
  __shared__ float red[16];
  const int t = threadIdx.x;
  const int v = hist[t];
  tmp[t] = v;
  __syncthreads();
  for (int off = 1; off < KCB; off <<= 1) {
    int x = 0;
    if (t >= off) x = tmp[t - off];
    __syncthreads();
    if (t >= off) tmp[t] += x;
    __syncthreads();
  }
  cursor[t] = tmp[t] - v;
  float o5 = 0.99f * emc[t] + 0.01f * (float)v;
  out5[t] = o5;
#pragma unroll
  for (int m = 32; m; m >>= 1) o5 += __shfl_xor(o5, m, 64);
  if ((t & 63) == 0) red[t >> 6] = o5;
  __syncthreads();
  if (t == 0) {
    float s = 0.f;
#pragma unroll
    for (int j = 0; j < 16; ++j) s += red[j];
    *ntot = s;
  }
}

// ---------------- scatter n's into per-code segments (+ key) ---------------
__global__ void k_scatter(const float* __restrict__ idx_f, int* __restrict__ cursor,
                          int* __restrict__ order, int* __restrict__ key) {
  const int n = blockIdx.x * blockDim.x + threadIdx.x;
  const int k = (int)idx_f[n];
  const int pos = atomicAdd(&cursor[k], 1);
  order[pos] = n;
  key[pos] = k;
}

// ------- chunk-parallel segmented reduction: dw -> out6 (+= 0.01*sum) ------
__global__ __launch_bounds__(128) void k_chunkreduce(
    const float* __restrict__ z_t, const int* __restrict__ order,
    const int* __restrict__ key, float* __restrict__ out6) {
  __shared__ int so[CHUNK], sk[CHUNK];
  const int t = threadIdx.x;
  const int base = blockIdx.x * CHUNK;
  if (t < CHUNK) { so[t] = order[base + t]; sk[t] = key[base + t]; }
  __syncthreads();
  int kprev = sk[0];
  float acc = 0.f;
  int i = 0;
  while (i < CHUNK) {
    if (i + 8 <= CHUNK && sk[i] == kprev && sk[i + 7] == kprev) {
      const float v0 = z_t[(size_t)so[i + 0] * 128 + t];
      const float v1 = z_t[(size_t)so[i + 1] * 128 + t];
      const float v2 = z_t[(size_t)so[i + 2] * 128 + t];
      const float v3 = z_t[(size_t)so[i + 3] * 128 + t];
      const float v4 = z_t[(size_t)so[i + 4] * 128 + t];
      const float v5 = z_t[(size_t)so[i + 5] * 128 + t];
      const float v6 = z_t[(size_t)so[i + 6] * 128 + t];
      const float v7 = z_t[(size_t)so[i + 7] * 128 + t];
      acc += ((v0 + v1) + (v2 + v3)) + ((v4 + v5) + (v6 + v7));
      i += 8;
    } else {
      const int kk = sk[i];
      if (kk != kprev) {
        atomicAdd(&out6[kprev * 128 + t], 0.01f * acc);
        acc = 0.f; kprev = kk;
      }
      acc += z_t[(size_t)so[i] * 128 + t];
      ++i;
    }
  }
  atomicAdd(&out6[kprev * 128 + t], 0.01f * acc);
}

// ------- gather quantized + per-block loss partial (no global atomics) -----
__global__ void k_quant_loss(const float* __restrict__ z, const float* __restrict__ cb,
                             const float* __restrict__ idx_f, float* __restrict__ out0,
                             float* __restrict__ partials) {
  __shared__ float red[4];
  float s = 0.f;
#pragma unroll
  for (int it = 0; it < 4; ++it) {
    const int t = blockIdx.x * 1024 + it * 256 + threadIdx.x;   // float4 index
    const int n = t >> 5;
    const int d4 = t & 31;
    const int k = (int)idx_f[n];
    const float4 q  = *(const float4*)(cb + k * DIM + d4 * 4);
    const float4 zv = *(const float4*)(z + ((size_t)t << 2));
    *(float4*)(out0 + ((size_t)t << 2)) = q;
    const float dx = q.x - zv.x, dy = q.y - zv.y, dz = q.z - zv.z, dw = q.w - zv.w;
    s += dx * dx + dy * dy + dz * dz + dw * dw;
  }
#pragma unroll
  for (int m = 32; m; m >>= 1) s += __shfl_xor(s, m, 64);
  const int lane = threadIdx.x & 63, wv = threadIdx.x >> 6;
  if (lane == 0) red[wv] = s;
  __syncthreads();
  if (threadIdx.x == 0) partials[blockIdx.x] = red[0] + red[1] + red[2] + red[3];
}

// ---------------- new_codebook + losses (block 511 reduces partials) -------
__global__ void k_final(const float* __restrict__ out5, const float* __restrict__ out6,
                        const float* __restrict__ ntot_p, const float* __restrict__ partials,
                        float* __restrict__ out4, float* __restrict__ out2,
                        float* __restrict__ out3) {
  __shared__ float red[4];
  const int i = blockIdx.x * blockDim.x + threadIdx.x;
  const float ntot = *ntot_p;
  const int k = i >> 7;
  const float w = (out5[k] + 1e-5f) / (ntot + KCB * 1e-5f) * ntot;
  out4[i] = out6[i] / w;
  if (blockIdx.x == 511) {
    const int t = threadIdx.x;
    float s = 0.f;
#pragma unroll
    for (int j = 0; j < QLBLOCKS / 256; ++j) s += partials[t + 256 * j];
#pragma unroll
    for (int m = 32; m; m >>= 1) s += __shfl_xor(s, m, 64);
    if ((t & 63) == 0) red[t >> 6] = s;
    __syncthreads();
    if (t == 0) {
      const float lv = (red[0] + red[1] + red[2] + red[3]) * (1.f / 8388608.f);
      *out2 = lv; *out3 = lv;
    }
  }
}

extern "C" void kernel_launch(void* const* d_in, const int* in_sizes, int n_in,
                              void* d_out, int out_size, void* d_ws, size_t ws_size,
                              hipStream_t stream) {
  (void)in_sizes; (void)n_in; (void)out_size; (void)ws_size;
  const float* z   = (const float*)d_in[0];
  const float* cb  = (const float*)d_in[1];
  const float* emc = (const float*)d_in[2];
  const float* emw = (const float*)d_in[3];
  float* out = (float*)d_out;
  float* out0 = out;                    // quantized_st  [8388608]
  float* out1 = out + 8388608;          // idx_map (float)[65536]
  float* out2 = out + 8454144;          // commitment_loss [1]
  float* out3 = out + 8454145;          // codebook_loss   [1]
  float* out4 = out + 8454146;          // new_codebook  [131072]
  float* out5 = out + 8585218;          // new_ema_count [1024]
  float* out6 = out + 8586242;          // new_ema_weight[131072]
  float* ws = (float*)d_ws;
  uint4* cbt      = (uint4*)ws;         // [16384] uint4 = 256KB
  // pcand [2*NVEC] uint2 = 1MB, aliases order/key (scatter runs after rescore)
  uint2* pcand    = (uint2*)(ws + 65536);
  int* order      = (int*)(ws + 65536); // [65536]
  int* key        = (int*)(ws + 131072);// [65536]  (pcand spans through 327680)
  float* cc       = ws + 327680;        // [1024]
  int* hist       = (int*)(ws + 328704);// [1024]
  int* cursor     = (int*)(ws + 329728);// [1024]
  float* ntot     = ws + 330752;        // [1]
  float* partials = ws + 331776;        // [2048]
  float* z_t = out0;                    // scratch: overwritten by k_quant_loss later

  hipMemsetAsync(hist, 0, KCB * sizeof(int), stream);
  hipLaunchKernelGGL(k_prep, dim3(64), dim3(256), 0, stream, cb, cbt, cc);
  hipLaunchKernelGGL(k_init_w, dim3(512), dim3(256), 0, stream, emw, out6);
  hipLaunchKernelGGL(k_argmin2, dim3(NVEC / 128 * 2), dim3(256), 0, stream,
                     z, cbt, cc, pcand, z_t);
  hipLaunchKernelGGL(k_rescore_hist, dim3(NVEC / 256), dim3(256), 0, stream,
                     z_t, cb, cc, pcand, out1, hist);
  hipLaunchKernelGGL(k_scan, dim3(1), dim3(1024), 0, stream, hist, emc, cursor,
                     out5, ntot);
  hipLaunchKernelGGL(k_scatter, dim3(NVEC / 256), dim3(256), 0, stream, out1, cursor,
                     order, key);
  hipLaunchKernelGGL(k_chunkreduce, dim3(NVEC / CHUNK), dim3(128), 0, stream,
                     z_t, order, key, out6);
  hipLaunchKernelGGL(k_quant_loss, dim3(QLBLOCKS), dim3(256), 0, stream, z, cb, out1,
                     out0, partials);
  hipLaunchKernelGGL(k_final, dim3(512), dim3(256), 0, stream, out5, out6, ntot,
                     partials, out4, out2, out3);
}

// Round 8
// 151.437 us; speedup vs baseline: 14.4903x; 1.0507x over previous
//
#include <hip/hip_runtime.h>

#define NVEC 65536   // B*H*W = 64*32*32
#define KCB  1024
#define DIM  128
#define HW   1024    // H*W
#define CHUNK 64
#define QLBLOCKS 2048

typedef __bf16 b16;
typedef b16 b16x8 __attribute__((ext_vector_type(8)));
typedef float f32x16 __attribute__((ext_vector_type(16)));

static __device__ __forceinline__ unsigned short f2bf(float f) {
  unsigned int x = __float_as_uint(f);
  unsigned int r = x + 0x7fffu + ((x >> 16) & 1u);   // RNE
  return (unsigned short)(r >> 16);
}

// ---- fused prep: cbt pack + out6=0.99*emw + hist=0 + ccb(f32) + cc64(f64) -
__global__ void k_prep(const float* __restrict__ cb, const float* __restrict__ emw,
                       uint4* __restrict__ cbt, float* __restrict__ ccb,
                       double* __restrict__ cc64, float* __restrict__ out6,
                       int* __restrict__ hist) {
  const int t = blockIdx.x * blockDim.x + threadIdx.x;   // 16384
  const int kc = t >> 11, u = t & 2047;
  const int code7 = u & 127, dch = u >> 7;
  const float* src = cb + (kc * 128 + code7) * 128 + dch * 8;
  const float4 x = *(const float4*)src;
  const float4 y = *(const float4*)(src + 4);
  uint4 o;
  o.x = (unsigned)f2bf(x.x) | ((unsigned)f2bf(x.y) << 16);
  o.y = (unsigned)f2bf(x.z) | ((unsigned)f2bf(x.w) << 16);
  o.z = (unsigned)f2bf(y.x) | ((unsigned)f2bf(y.y) << 16);
  o.w = (unsigned)f2bf(y.z) | ((unsigned)f2bf(y.w) << 16);
  cbt[t] = o;
  // out6 init: out6 offset is 8B- but not 16B-aligned -> float2 stores
  const float4 e0 = *(const float4*)(emw + (size_t)t * 8);
  const float4 e1 = *(const float4*)(emw + (size_t)t * 8 + 4);
  *(float2*)(out6 + (size_t)t * 8 + 0) = make_float2(0.99f * e0.x, 0.99f * e0.y);
  *(float2*)(out6 + (size_t)t * 8 + 2) = make_float2(0.99f * e0.z, 0.99f * e0.w);
  *(float2*)(out6 + (size_t)t * 8 + 4) = make_float2(0.99f * e1.x, 0.99f * e1.y);
  *(float2*)(out6 + (size_t)t * 8 + 6) = make_float2(0.99f * e1.z, 0.99f * e1.w);
  if (t < KCB) hist[t] = 0;
  if (blockIdx.x < 4) {
    const int k = blockIdx.x * 256 + threadIdx.x;
    const float* row = cb + k * DIM;
    double s = 0.0;
#pragma unroll 8
    for (int j = 0; j < DIM; ++j) {
      const double v = (double)row[j];
      s = fma(v, v, s);
    }
    cc64[k] = s;
    ccb[k] = 512.f - 0.5f * (float)s;   // bias keeps packed scores positive
  }
}

// ---------------- transpose z[b][d][hw] -> z_t[(b*1024+hw)][d] (f32) -------
// FIXED: write phase stays within the 64x64 tile (R2-R6 version indexed
// tile[d] for d up to 127 -> OOB LDS reads + racy OOB z_t writes).
__global__ void k_transpose(const float* __restrict__ z, float* __restrict__ z_t) {
  __shared__ float tile[64][65];
  const int t = threadIdx.x;
  const int b = blockIdx.z;
  const int d0 = blockIdx.y * 64;
  const int hw0 = blockIdx.x * 64;
  const float* src = z + (size_t)b * 131072 + d0 * 1024 + hw0;
  {
    const int hw4 = (t & 15) * 4;
    const int dr = t >> 4;
#pragma unroll
    for (int j = 0; j < 4; ++j) {
      const int d = dr + 16 * j;
      const float4 v = *(const float4*)(src + d * 1024 + hw4);
      tile[d][hw4 + 0] = v.x; tile[d][hw4 + 1] = v.y;
      tile[d][hw4 + 2] = v.z; tile[d][hw4 + 3] = v.w;
    }
  }
  __syncthreads();
  float* dst = z_t + (size_t)b * 131072 + hw0 * 128 + d0;
  {
    const int d4 = (t & 15) * 4;       // 16 positions x 4 = 64 dims (in-bounds)
    const int hwr = t >> 4;            // 16 hw rows
#pragma unroll
    for (int j = 0; j < 4; ++j) {
      const int hw = hwr + 16 * j;
      float4 v;
      v.x = tile[d4 + 0][hw]; v.y = tile[d4 + 1][hw];
      v.z = tile[d4 + 2][hw]; v.w = tile[d4 + 3][hw];
      *(float4*)(dst + hw * 128 + d4) = v;
    }
  }
}

// ---- MFMA argmin v3: 64-row tiles, all 1024 codes, biased-max packed top-2
// score(bias) = 512 - cc/2 + dot straight out of the MFMA (C-in=ccb).
// Positive floats => u32 bits monotone; index stored inverted (1023-k) in the
// low 10 bits so max-ties prefer the smaller code.
__global__ __launch_bounds__(256, 4) void k_argmin3(
    const float* __restrict__ z, const uint4* __restrict__ cbt,
    const float* __restrict__ ccb, uint2* __restrict__ pcand) {
  __shared__ uint4 Bs[2048];                       // 32 KiB: u = dchunk*128 + code7
  const int tid = threadIdx.x;
  const int l = tid & 63, wv = tid >> 6;
  const int g = l >> 5;                            // k-slice group
  const int lm = l & 31;                           // row-lane / code-lane
  const int wr = (wv & 1) * 32;
  const int wc = wv >> 1;
  const int n0 = blockIdx.x * 64;
  const int b = n0 >> 10;
  const int hw = (n0 & (HW - 1)) + wr + lm;        // spatial row (64 | 1024)
  const float* zp = z + (size_t)b * 131072 + hw;

  uint4 afrag[8];
#pragma unroll
  for (int ks = 0; ks < 8; ++ks) {
    const int d0 = ks * 16 + g * 8;
    const float v0 = zp[(d0 + 0) * 1024], v1 = zp[(d0 + 1) * 1024];
    const float v2 = zp[(d0 + 2) * 1024], v3 = zp[(d0 + 3) * 1024];
    const float v4 = zp[(d0 + 4) * 1024], v5 = zp[(d0 + 5) * 1024];
    const float v6 = zp[(d0 + 6) * 1024], v7 = zp[(d0 + 7) * 1024];
    afrag[ks].x = (unsigned)f2bf(v0) | ((unsigned)f2bf(v1) << 16);
    afrag[ks].y = (unsigned)f2bf(v2) | ((unsigned)f2bf(v3) << 16);
    afrag[ks].z = (unsigned)f2bf(v4) | ((unsigned)f2bf(v5) << 16);
    afrag[ks].w = (unsigned)f2bf(v6) | ((unsigned)f2bf(v7) << 16);
  }

  unsigned pm1[16], pm2[16];
#pragma unroll
  for (int r = 0; r < 16; ++r) { pm1[r] = 0u; pm2[r] = 0u; }

  for (int kc = 0; kc < 8; ++kc) {
    __syncthreads();                               // Bs readers of prev chunk done
#pragma unroll
    for (int i = 0; i < 8; ++i) {
      __builtin_amdgcn_global_load_lds(&cbt[kc * 2048 + wv * 512 + i * 64 + l],
                                       &Bs[wv * 512 + i * 64], 16, 0, 0);
    }
    const float cv0 = ccb[kc * 128 + (wc * 2 + 0) * 32 + lm];
    const float cv1 = ccb[kc * 128 + (wc * 2 + 1) * 32 + lm];
    __syncthreads();                               // staging landed

    f32x16 a0, a1;
#pragma unroll
    for (int j = 0; j < 16; ++j) { a0[j] = cv0; a1[j] = cv1; }
#pragma unroll
    for (int ks = 0; ks < 8; ++ks) {
      const b16x8 av = *reinterpret_cast<const b16x8*>(&afrag[ks]);
      const b16x8 bv0 = *reinterpret_cast<const b16x8*>(&Bs[(ks * 2 + g) * 128 + (wc * 2) * 32 + lm]);
      const b16x8 bv1 = *reinterpret_cast<const b16x8*>(&Bs[(ks * 2 + g) * 128 + (wc * 2 + 1) * 32 + lm]);
      a0 = __builtin_amdgcn_mfma_f32_32x32x16_bf16(av, bv0, a0, 0, 0, 0);
      a1 = __builtin_amdgcn_mfma_f32_32x32x16_bf16(av, bv1, a1, 0, 0, 0);
    }
    const unsigned ci0 = 1023u - (unsigned)(kc * 128 + (wc * 2) * 32 + lm);
    const unsigned ci1 = ci0 - 32u;
#pragma unroll
    for (int r = 0; r < 16; ++r) {
      {
        const unsigned uu = ((__float_as_uint(a0[r]) + 0x200u) & 0xFFFFFC00u) | ci0;
        const unsigned t = pm1[r] < uu ? pm1[r] : uu;
        pm1[r] = pm1[r] > uu ? pm1[r] : uu;
        pm2[r] = pm2[r] > t ? pm2[r] : t;
      }
      {
        const unsigned uu = ((__float_as_uint(a1[r]) + 0x200u) & 0xFFFFFC00u) | ci1;
        const unsigned t = pm1[r] < uu ? pm1[r] : uu;
        pm1[r] = pm1[r] > uu ? pm1[r] : uu;
        pm2[r] = pm2[r] > t ? pm2[r] : t;
      }
    }
  }

  // top-2 (max-order) merge across the 32 code-lanes
#pragma unroll
  for (int r = 0; r < 16; ++r) {
    unsigned u1 = pm1[r], u2 = pm2[r];
#pragma unroll
    for (int m = 1; m < 32; m <<= 1) {
      const unsigned o1 = (unsigned)__shfl_xor((int)u1, m, 64);
      const unsigned o2 = (unsigned)__shfl_xor((int)u2, m, 64);
      const unsigned s = u1 < o1 ? u1 : o1;
      u1 = u1 > o1 ? u1 : o1;
      u2 = u2 > o2 ? u2 : o2;
      u2 = u2 > s ? u2 : s;
    }
    if (lm == 0) {
      const int rowg = n0 + wr + (r & 3) + 8 * (r >> 2) + 4 * g;
      pcand[wc * NVEC + rowg] = make_uint2(u1, u2);
    }
  }
}

// ---- exact f64 rescore of ALL 4 candidates + idx + LDS histogram ----------
// Reproduces the numpy-f64 reference ordering (kills near-tie flips).
__global__ void k_rescore_hist(const float* __restrict__ z_t, const float* __restrict__ cb,
                               const double* __restrict__ cc64,
                               const uint2* __restrict__ pcand,
                               float* __restrict__ out1, int* __restrict__ hist) {
  __shared__ int h[KCB];
  const int tid = threadIdx.x;
#pragma unroll
  for (int j = 0; j < 4; ++j) h[tid + 256 * j] = 0;
  __syncthreads();
  const int n = blockIdx.x * 256 + tid;
  const uint2 A = pcand[n];
  const uint2 Bq = pcand[NVEC + n];
  int ks[4];
  ks[0] = 1023 - (int)(A.x & 1023u);
  ks[1] = 1023 - (int)(A.y & 1023u);
  ks[2] = 1023 - (int)(Bq.x & 1023u);
  ks[3] = 1023 - (int)(Bq.y & 1023u);
  const float4* zr = (const float4*)(z_t + (size_t)n * DIM);
  const float4* c0 = (const float4*)(cb + ks[0] * DIM);
  const float4* c1 = (const float4*)(cb + ks[1] * DIM);
  const float4* c2 = (const float4*)(cb + ks[2] * DIM);
  const float4* c3 = (const float4*)(cb + ks[3] * DIM);
  double d0 = 0.0, d1 = 0.0, d2 = 0.0, d3 = 0.0;
#pragma unroll 4
  for (int j = 0; j < DIM / 4; ++j) {
    const float4 zv = zr[j];
    const double zx = zv.x, zy = zv.y, zz = zv.z, zw = zv.w;
    const float4 a = c0[j];
    d0 = fma(zx, (double)a.x, d0); d0 = fma(zy, (double)a.y, d0);
    d0 = fma(zz, (double)a.z, d0); d0 = fma(zw, (double)a.w, d0);
    const float4 b = c1[j];
    d1 = fma(zx, (double)b.x, d1); d1 = fma(zy, (double)b.y, d1);
    d1 = fma(zz, (double)b.z, d1); d1 = fma(zw, (double)b.w, d1);
    const float4 c = c2[j];
    d2 = fma(zx, (double)c.x, d2); d2 = fma(zy, (double)c.y, d2);
    d2 = fma(zz, (double)c.z, d2); d2 = fma(zw, (double)c.w, d2);
    const float4 e = c3[j];
    d3 = fma(zx, (double)e.x, d3); d3 = fma(zy, (double)e.y, d3);
    d3 = fma(zz, (double)e.z, d3); d3 = fma(zw, (double)e.w, d3);
  }
  double s[4];
  s[0] = fma(-2.0, d0, cc64[ks[0]]);
  s[1] = fma(-2.0, d1, cc64[ks[1]]);
  s[2] = fma(-2.0, d2, cc64[ks[2]]);
  s[3] = fma(-2.0, d3, cc64[ks[3]]);
  int kw = ks[0]; double sw = s[0];
#pragma unroll
  for (int c = 1; c < 4; ++c) {
    if (s[c] < sw || (s[c] == sw && ks[c] < kw)) { sw = s[c]; kw = ks[c]; }
  }
  out1[n] = (float)kw;
  atomicAdd(&h[kw], 1);
  __syncthreads();
#pragma unroll
  for (int j = 0; j < 4; ++j) {
    const int v = h[tid + 256 * j];
    if (v) atomicAdd(&hist[tid + 256 * j], v);
  }
}

// ---- exclusive scan over 1024 bins + out5 + ntot (single block) -----------
__global__ void k_scan(const int* __restrict__ hist, const float* __restrict__ emc,
                       int* __restrict__ cursor, float* __restrict__ out5,
                       float* __restrict__ ntot) {
  __shared__ int tmp[KCB];
  __shared__ float red[16];
  const int t = threadIdx.x;
  const int v = hist[t];
  tmp[t] = v;
  __syncthreads();
  for (int off = 1; off < KCB; off <<= 1) {
    int x = 0;
    if (t >= off) x = tmp[t - off];
    __syncthreads();
    if (t >= off) tmp[t] += x;
    __syncthreads();
  }
  cursor[t] = tmp[t] - v;
  float o5 = 0.99f * emc[t] + 0.01f * (float)v;
  out5[t] = o5;
#pragma unroll
  for (int m = 32; m; m >>= 1) o5 += __shfl_xor(o5, m, 64);
  if ((t & 63) == 0) red[t >> 6] = o5;
  __syncthreads();
  if (t == 0) {
    float s = 0.f;
#pragma unroll
    for (int j = 0; j < 16; ++j) s += red[j];
    *ntot = s;
  }
}

// ---------------- scatter n's into per-code segments (+ key) ---------------
__global__ void k_scatter(const float* __restrict__ idx_f, int* __restrict__ cursor,
                          int* __restrict__ order, int* __restrict__ key) {
  const int n = blockIdx.x * blockDim.x + threadIdx.x;
  const int k = (int)idx_f[n];
  const int pos = atomicAdd(&cursor[k], 1);
  order[pos] = n;
  key[pos] = k;
}

// ------- chunk-parallel segmented reduction: dw -> out6 (+= 0.01*sum) ------
__global__ __launch_bounds__(128) void k_chunkreduce(
    const float* __restrict__ z_t, const int* __restrict__ order,
    const int* __restrict__ key, float* __restrict__ out6) {
  __shared__ int so[CHUNK], sk[CHUNK];
  const int t = threadIdx.x;
  const int base = blockIdx.x * CHUNK;
  if (t < CHUNK) { so[t] = order[base + t]; sk[t] = key[base + t]; }
  __syncthreads();
  int kprev = sk[0];
  float acc = 0.f;
  int i = 0;
  while (i < CHUNK) {
    if (i + 8 <= CHUNK && sk[i] == kprev && sk[i + 7] == kprev) {
      const float v0 = z_t[(size_t)so[i + 0] * 128 + t];
      const float v1 = z_t[(size_t)so[i + 1] * 128 + t];
      const float v2 = z_t[(size_t)so[i + 2] * 128 + t];
      const float v3 = z_t[(size_t)so[i + 3] * 128 + t];
      const float v4 = z_t[(size_t)so[i + 4] * 128 + t];
      const float v5 = z_t[(size_t)so[i + 5] * 128 + t];
      const float v6 = z_t[(size_t)so[i + 6] * 128 + t];
      const float v7 = z_t[(size_t)so[i + 7] * 128 + t];
      acc += ((v0 + v1) + (v2 + v3)) + ((v4 + v5) + (v6 + v7));
      i += 8;
    } else {
      const int kk = sk[i];
      if (kk != kprev) {
        atomicAdd(&out6[kprev * 128 + t], 0.01f * acc);
        acc = 0.f; kprev = kk;
      }
      acc += z_t[(size_t)so[i] * 128 + t];
      ++i;
    }
  }
  atomicAdd(&out6[kprev * 128 + t], 0.01f * acc);
}

// ------- gather quantized + per-block loss partial (no global atomics) -----
__global__ void k_quant_loss(const float* __restrict__ z, const float* __restrict__ cb,
                             const float* __restrict__ idx_f, float* __restrict__ out0,
                             float* __restrict__ partials) {
  __shared__ float red[4];
  float s = 0.f;
#pragma unroll
  for (int it = 0; it < 4; ++it) {
    const int t = blockIdx.x * 1024 + it * 256 + threadIdx.x;   // float4 index
    const int n = t >> 5;
    const int d4 = t & 31;
    const int k = (int)idx_f[n];
    const float4 q  = *(const float4*)(cb + k * DIM + d4 * 4);
    const float4 zv = *(const float4*)(z + ((size_t)t << 2));
    *(float4*)(out0 + ((size_t)t << 2)) = q;
    const float dx = q.x - zv.x, dy = q.y - zv.y, dz = q.z - zv.z, dw = q.w - zv.w;
    s += dx * dx + dy * dy + dz * dz + dw * dw;
  }
#pragma unroll
  for (int m = 32; m; m >>= 1) s += __shfl_xor(s, m, 64);
  const int lane = threadIdx.x & 63, wv = threadIdx.x >> 6;
  if (lane == 0) red[wv] = s;
  __syncthreads();
  if (threadIdx.x == 0) partials[blockIdx.x] = red[0] + red[1] + red[2] + red[3];
}

// ---------------- new_codebook + losses (block 511 reduces partials) -------
__global__ void k_final(const float* __restrict__ out5, const float* __restrict__ out6,
                        const float* __restrict__ ntot_p, const float* __restrict__ partials,
                        float* __restrict__ out4, float* __restrict__ out2,
                        float* __restrict__ out3) {
  __shared__ float red[4];
  const int i = blockIdx.x * blockDim.x + threadIdx.x;
  const float ntot = *ntot_p;
  const int k = i >> 7;
  const float w = (out5[k] + 1e-5f) / (ntot + KCB * 1e-5f) * ntot;
  out4[i] = out6[i] / w;
  if (blockIdx.x == 511) {
    const int t = threadIdx.x;
    float s = 0.f;
#pragma unroll
    for (int j = 0; j < QLBLOCKS / 256; ++j) s += partials[t + 256 * j];
#pragma unroll
    for (int m = 32; m; m >>= 1) s += __shfl_xor(s, m, 64);
    if ((t & 63) == 0) red[t >> 6] = s;
    __syncthreads();
    if (t == 0) {
      const float lv = (red[0] + red[1] + red[2] + red[3]) * (1.f / 8388608.f);
      *out2 = lv; *out3 = lv;
    }
  }
}

extern "C" void kernel_launch(void* const* d_in, const int* in_sizes, int n_in,
                              void* d_out, int out_size, void* d_ws, size_t ws_size,
                              hipStream_t stream) {
  (void)in_sizes; (void)n_in; (void)out_size; (void)ws_size;
  const float* z   = (const float*)d_in[0];
  const float* cb  = (const float*)d_in[1];
  const float* emc = (const float*)d_in[2];
  const float* emw = (const float*)d_in[3];
  float* out = (float*)d_out;
  float* out0 = out;                    // quantized_st  [8388608]
  float* out1 = out + 8388608;          // idx_map (float)[65536]
  float* out2 = out + 8454144;          // commitment_loss [1]
  float* out3 = out + 8454145;          // codebook_loss   [1]
  float* out4 = out + 8454146;          // new_codebook  [131072]
  float* out5 = out + 8585218;          // new_ema_count [1024]
  float* out6 = out + 8586242;          // new_ema_weight[131072]
  float* ws = (float*)d_ws;
  uint4* cbt      = (uint4*)ws;         // [16384] uint4 = 256KB
  // pcand [2*NVEC] uint2 = 1MB, aliases order/key (scatter runs after rescore)
  uint2* pcand    = (uint2*)(ws + 65536);
  int* order      = (int*)(ws + 65536); // [65536]
  int* key        = (int*)(ws + 131072);// [65536]  (pcand spans through 327680)
  float* ccb      = ws + 327680;        // [1024]
  int* hist       = (int*)(ws + 328704);// [1024]
  int* cursor     = (int*)(ws + 329728);// [1024]
  float* ntot     = ws + 330752;        // [1]
  float* partials = ws + 331776;        // [2048]
  double* cc64    = (double*)(ws + 333824);  // [1024] doubles (8B-aligned)
  float* z_t = out0;                    // scratch: overwritten by k_quant_loss later

  hipLaunchKernelGGL(k_prep, dim3(64), dim3(256), 0, stream, cb, emw, cbt, ccb,
                     cc64, out6, hist);
  hipLaunchKernelGGL(k_transpose, dim3(16, 2, 64), dim3(256), 0, stream, z, z_t);
  hipLaunchKernelGGL(k_argmin3, dim3(NVEC / 64), dim3(256), 0, stream,
                     z, cbt, ccb, pcand);
  hipLaunchKernelGGL(k_rescore_hist, dim3(NVEC / 256), dim3(256), 0, stream,
                     z_t, cb, cc64, pcand, out1, hist);
  hipLaunchKernelGGL(k_scan, dim3(1), dim3(1024), 0, stream, hist, emc, cursor,
                     out5, ntot);
  hipLaunchKernelGGL(k_scatter, dim3(NVEC / 256), dim3(256), 0, stream, out1, cursor,
                     order, key);
  hipLaunchKernelGGL(k_chunkreduce, dim3(NVEC / CHUNK), dim3(128), 0, stream,
                     z_t, order, key, out6);
  hipLaunchKernelGGL(k_quant_loss, dim3(QLBLOCKS), dim3(256), 0, stream, z, cb, out1,
                     out0, partials);
  hipLaunchKernelGGL(k_final, dim3(512), dim3(256), 0, stream, out5, out6, ntot,
                     partials, out4, out2, out3);
}

// Round 9
// 138.926 us; speedup vs baseline: 15.7951x; 1.0901x over previous
//
#include <hip/hip_runtime.h>

#define NVEC 65536   // B*H*W = 64*32*32
#define KCB  1024
#define DIM  128
#define HW   1024    // H*W
#define CHUNK 64
#define NCHUNKS (NVEC / CHUNK)

typedef __bf16 b16;
typedef b16 b16x8 __attribute__((ext_vector_type(8)));
typedef float f32x16 __attribute__((ext_vector_type(16)));

static __device__ __forceinline__ unsigned short f2bf(float f) {
  unsigned int x = __float_as_uint(f);
  unsigned int r = x + 0x7fffu + ((x >> 16) & 1u);   // RNE
  return (unsigned short)(r >> 16);
}

// ---- fused prep: cbt pack + out6=0.99*emw + hist=0 + ccb(f32) + cc64(f64) -
__global__ void k_prep(const float* __restrict__ cb, const float* __restrict__ emw,
                       uint4* __restrict__ cbt, float* __restrict__ ccb,
                       double* __restrict__ cc64, float* __restrict__ out6,
                       int* __restrict__ hist) {
  const int t = blockIdx.x * blockDim.x + threadIdx.x;   // 16384
  const int kc = t >> 11, u = t & 2047;
  const int code7 = u & 127, dch = u >> 7;
  const float* src = cb + (kc * 128 + code7) * 128 + dch * 8;
  const float4 x = *(const float4*)src;
  const float4 y = *(const float4*)(src + 4);
  uint4 o;
  o.x = (unsigned)f2bf(x.x) | ((unsigned)f2bf(x.y) << 16);
  o.y = (unsigned)f2bf(x.z) | ((unsigned)f2bf(x.w) << 16);
  o.z = (unsigned)f2bf(y.x) | ((unsigned)f2bf(y.y) << 16);
  o.w = (unsigned)f2bf(y.z) | ((unsigned)f2bf(y.w) << 16);
  cbt[t] = o;
  // out6 init: out6 offset is 8B- but not 16B-aligned -> float2 stores
  const float4 e0 = *(const float4*)(emw + (size_t)t * 8);
  const float4 e1 = *(const float4*)(emw + (size_t)t * 8 + 4);
  *(float2*)(out6 + (size_t)t * 8 + 0) = make_float2(0.99f * e0.x, 0.99f * e0.y);
  *(float2*)(out6 + (size_t)t * 8 + 2) = make_float2(0.99f * e0.z, 0.99f * e0.w);
  *(float2*)(out6 + (size_t)t * 8 + 4) = make_float2(0.99f * e1.x, 0.99f * e1.y);
  *(float2*)(out6 + (size_t)t * 8 + 6) = make_float2(0.99f * e1.z, 0.99f * e1.w);
  if (t < KCB) hist[t] = 0;
  if (blockIdx.x < 4) {
    const int k = blockIdx.x * 256 + threadIdx.x;
    const float* row = cb + k * DIM;
    double s = 0.0;
#pragma unroll 8
    for (int j = 0; j < DIM; ++j) {
      const double v = (double)row[j];
      s = fma(v, v, s);
    }
    cc64[k] = s;
    ccb[k] = 512.f - 0.5f * (float)s;   // bias keeps packed scores positive
  }
}

// ---- MFMA argmin + fused transpose: 64-row tiles, all 1024 codes ----------
// Phase 0: stage z tile [128 d][64 hw] in LDS (padded 65) from coalesced
// float4 loads. Phase 1: write z_t with full-128B-line stores (8 lanes x 16B
// contiguous per row -- avoids R5's partial-line write amplification) and
// build afrag from LDS. Then the kc-loop reuses the same LDS as Bs.
// score(bias) = 512 - cc/2 + dot straight out of the MFMA (C-in=ccb);
// positive => u32-monotone; index inverted in low 10 bits (max-tie -> min k).
__global__ __launch_bounds__(256, 4) void k_argmin3t(
    const float* __restrict__ z, const uint4* __restrict__ cbt,
    const float* __restrict__ ccb, uint2* __restrict__ pcand,
    float* __restrict__ z_t) {
  __shared__ __align__(16) char smem[128 * 65 * 4];   // 33.3 KB
  float (*zs)[65] = (float(*)[65])smem;
  uint4* Bs = (uint4*)smem;                            // reused after phase 1
  const int tid = threadIdx.x;
  const int l = tid & 63, wv = tid >> 6;
  const int g = l >> 5;                            // k-slice group
  const int lm = l & 31;                           // row-lane / code-lane
  const int wr = (wv & 1) * 32;
  const int wc = wv >> 1;
  const int n0 = blockIdx.x * 64;
  const int b = n0 >> 10;
  const int hwbase = n0 & (HW - 1);

  // ---- phase 0: coalesced stage of the z tile into LDS
  {
    const int hw4 = (tid & 15) * 4;
    const int dr = tid >> 4;
    const float* src = z + (size_t)b * 131072 + hwbase + hw4;
#pragma unroll
    for (int j = 0; j < 8; ++j) {
      const int d = dr + 16 * j;
      const float4 v = *(const float4*)(src + d * 1024);
      zs[d][hw4 + 0] = v.x; zs[d][hw4 + 1] = v.y;
      zs[d][hw4 + 2] = v.z; zs[d][hw4 + 3] = v.w;
    }
  }
  __syncthreads();

  // ---- phase 1a: z_t rows, full-line stores (lane d4=t&7 covers 128B/8 lanes)
#pragma unroll
  for (int jj = 0; jj < 2; ++jj) {
    const int row = (tid >> 3) + 32 * jj;
    float* dst = z_t + ((size_t)(n0 + row)) * 128;
#pragma unroll
    for (int j = 0; j < 4; ++j) {
      const int d = (j * 8 + (tid & 7)) * 4;
      float4 v;
      v.x = zs[d + 0][row]; v.y = zs[d + 1][row];
      v.z = zs[d + 2][row]; v.w = zs[d + 3][row];
      *(float4*)(dst + d) = v;
    }
  }
  // ---- phase 1b: afrag from LDS
  uint4 afrag[8];
  {
    const int row = wr + lm;
#pragma unroll
    for (int ks = 0; ks < 8; ++ks) {
      const int d0 = ks * 16 + g * 8;
      afrag[ks].x = (unsigned)f2bf(zs[d0 + 0][row]) | ((unsigned)f2bf(zs[d0 + 1][row]) << 16);
      afrag[ks].y = (unsigned)f2bf(zs[d0 + 2][row]) | ((unsigned)f2bf(zs[d0 + 3][row]) << 16);
      afrag[ks].z = (unsigned)f2bf(zs[d0 + 4][row]) | ((unsigned)f2bf(zs[d0 + 5][row]) << 16);
      afrag[ks].w = (unsigned)f2bf(zs[d0 + 6][row]) | ((unsigned)f2bf(zs[d0 + 7][row]) << 16);
    }
  }

  unsigned pm1[16], pm2[16];
#pragma unroll
  for (int r = 0; r < 16; ++r) { pm1[r] = 0u; pm2[r] = 0u; }

  for (int kc = 0; kc < 8; ++kc) {
    __syncthreads();    // kc=0: zs readers done; kc>0: Bs readers done
#pragma unroll
    for (int i = 0; i < 8; ++i) {
      __builtin_amdgcn_global_load_lds(&cbt[kc * 2048 + wv * 512 + i * 64 + l],
                                       &Bs[wv * 512 + i * 64], 16, 0, 0);
    }
    const float cv0 = ccb[kc * 128 + (wc * 2 + 0) * 32 + lm];
    const float cv1 = ccb[kc * 128 + (wc * 2 + 1) * 32 + lm];
    __syncthreads();                               // staging landed

    f32x16 a0, a1;
#pragma unroll
    for (int j = 0; j < 16; ++j) { a0[j] = cv0; a1[j] = cv1; }
#pragma unroll
    for (int ks = 0; ks < 8; ++ks) {
      const b16x8 av = *reinterpret_cast<const b16x8*>(&afrag[ks]);
      const b16x8 bv0 = *reinterpret_cast<const b16x8*>(&Bs[(ks * 2 + g) * 128 + (wc * 2) * 32 + lm]);
      const b16x8 bv1 = *reinterpret_cast<const b16x8*>(&Bs[(ks * 2 + g) * 128 + (wc * 2 + 1) * 32 + lm]);
      a0 = __builtin_amdgcn_mfma_f32_32x32x16_bf16(av, bv0, a0, 0, 0, 0);
      a1 = __builtin_amdgcn_mfma_f32_32x32x16_bf16(av, bv1, a1, 0, 0, 0);
    }
    const unsigned ci0 = 1023u - (unsigned)(kc * 128 + (wc * 2) * 32 + lm);
    const unsigned ci1 = ci0 - 32u;
#pragma unroll
    for (int r = 0; r < 16; ++r) {
      {
        const unsigned uu = ((__float_as_uint(a0[r]) + 0x200u) & 0xFFFFFC00u) | ci0;
        const unsigned t = pm1[r] < uu ? pm1[r] : uu;
        pm1[r] = pm1[r] > uu ? pm1[r] : uu;
        pm2[r] = pm2[r] > t ? pm2[r] : t;
      }
      {
        const unsigned uu = ((__float_as_uint(a1[r]) + 0x200u) & 0xFFFFFC00u) | ci1;
        const unsigned t = pm1[r] < uu ? pm1[r] : uu;
        pm1[r] = pm1[r] > uu ? pm1[r] : uu;
        pm2[r] = pm2[r] > t ? pm2[r] : t;
      }
    }
  }

  // top-2 (max-order) merge across the 32 code-lanes
#pragma unroll
  for (int r = 0; r < 16; ++r) {
    unsigned u1 = pm1[r], u2 = pm2[r];
#pragma unroll
    for (int m = 1; m < 32; m <<= 1) {
      const unsigned o1 = (unsigned)__shfl_xor((int)u1, m, 64);
      const unsigned o2 = (unsigned)__shfl_xor((int)u2, m, 64);
      const unsigned s = u1 < o1 ? u1 : o1;
      u1 = u1 > o1 ? u1 : o1;
      u2 = u2 > o2 ? u2 : o2;
      u2 = u2 > s ? u2 : s;
    }
    if (lm == 0) {
      const int rowg = n0 + wr + (r & 3) + 8 * (r >> 2) + 4 * g;
      pcand[wc * NVEC + rowg] = make_uint2(u1, u2);
    }
  }
}

// ---- exact f64 rescore of ALL 4 candidates + idx + LDS histogram ----------
__global__ void k_rescore_hist(const float* __restrict__ z_t, const float* __restrict__ cb,
                               const double* __restrict__ cc64,
                               const uint2* __restrict__ pcand,
                               float* __restrict__ out1, int* __restrict__ hist) {
  __shared__ int h[KCB];
  const int tid = threadIdx.x;
#pragma unroll
  for (int j = 0; j < 4; ++j) h[tid + 256 * j] = 0;
  __syncthreads();
  const int n = blockIdx.x * 256 + tid;
  const uint2 A = pcand[n];
  const uint2 Bq = pcand[NVEC + n];
  int ks[4];
  ks[0] = 1023 - (int)(A.x & 1023u);
  ks[1] = 1023 - (int)(A.y & 1023u);
  ks[2] = 1023 - (int)(Bq.x & 1023u);
  ks[3] = 1023 - (int)(Bq.y & 1023u);
  const float4* zr = (const float4*)(z_t + (size_t)n * DIM);
  const float4* c0 = (const float4*)(cb + ks[0] * DIM);
  const float4* c1 = (const float4*)(cb + ks[1] * DIM);
  const float4* c2 = (const float4*)(cb + ks[2] * DIM);
  const float4* c3 = (const float4*)(cb + ks[3] * DIM);
  double d0 = 0.0, d1 = 0.0, d2 = 0.0, d3 = 0.0;
#pragma unroll 4
  for (int j = 0; j < DIM / 4; ++j) {
    const float4 zv = zr[j];
    const double zx = zv.x, zy = zv.y, zz = zv.z, zw = zv.w;
    const float4 a = c0[j];
    d0 = fma(zx, (double)a.x, d0); d0 = fma(zy, (double)a.y, d0);
    d0 = fma(zz, (double)a.z, d0); d0 = fma(zw, (double)a.w, d0);
    const float4 b = c1[j];
    d1 = fma(zx, (double)b.x, d1); d1 = fma(zy, (double)b.y, d1);
    d1 = fma(zz, (double)b.z, d1); d1 = fma(zw, (double)b.w, d1);
    const float4 c = c2[j];
    d2 = fma(zx, (double)c.x, d2); d2 = fma(zy, (double)c.y, d2);
    d2 = fma(zz, (double)c.z, d2); d2 = fma(zw, (double)c.w, d2);
    const float4 e = c3[j];
    d3 = fma(zx, (double)e.x, d3); d3 = fma(zy, (double)e.y, d3);
    d3 = fma(zz, (double)e.z, d3); d3 = fma(zw, (double)e.w, d3);
  }
  double s[4];
  s[0] = fma(-2.0, d0, cc64[ks[0]]);
  s[1] = fma(-2.0, d1, cc64[ks[1]]);
  s[2] = fma(-2.0, d2, cc64[ks[2]]);
  s[3] = fma(-2.0, d3, cc64[ks[3]]);
  int kw = ks[0]; double sw = s[0];
#pragma unroll
  for (int c = 1; c < 4; ++c) {
    if (s[c] < sw || (s[c] == sw && ks[c] < kw)) { sw = s[c]; kw = ks[c]; }
  }
  out1[n] = (float)kw;
  atomicAdd(&h[kw], 1);
  __syncthreads();
#pragma unroll
  for (int j = 0; j < 4; ++j) {
    const int v = h[tid + 256 * j];
    if (v) atomicAdd(&hist[tid + 256 * j], v);
  }
}

// ---- exclusive scan over 1024 bins + out5 + ntot (single block) -----------
__global__ void k_scan(const int* __restrict__ hist, const float* __restrict__ emc,
                       int* __restrict__ cursor, float* __restrict__ out5,
                       float* __restrict__ ntot) {
  __shared__ int tmp[KCB];
  __shared__ float red[16];
  const int t = threadIdx.x;
  const int v = hist[t];
  tmp[t] = v;
  __syncthreads();
  for (int off = 1; off < KCB; off <<= 1) {
    int x = 0;
    if (t >= off) x = tmp[t - off];
    __syncthreads();
    if (t >= off) tmp[t] += x;
    __syncthreads();
  }
  cursor[t] = tmp[t] - v;
  float o5 = 0.99f * emc[t] + 0.01f * (float)v;
  out5[t] = o5;
#pragma unroll
  for (int m = 32; m; m >>= 1) o5 += __shfl_xor(o5, m, 64);
  if ((t & 63) == 0) red[t >> 6] = o5;
  __syncthreads();
  if (t == 0) {
    float s = 0.f;
#pragma unroll
    for (int j = 0; j < 16; ++j) s += red[j];
    *ntot = s;
  }
}

// ---------------- scatter n's into per-code segments (+ key) ---------------
__global__ void k_scatter(const float* __restrict__ idx_f, int* __restrict__ cursor,
                          int* __restrict__ order, int* __restrict__ key) {
  const int n = blockIdx.x * blockDim.x + threadIdx.x;
  const int k = (int)idx_f[n];
  const int pos = atomicAdd(&cursor[k], 1);
  order[pos] = n;
  key[pos] = k;
}

// ---- chunk-parallel segmented reduce + quantized write + loss partial -----
// zq aliases z_t (read) and out0 (write): thread t owns dim t of each row,
// reads z before overwriting with cb[k][t] at the same address.
__global__ __launch_bounds__(128) void k_chunkreduce_q(
    float* zq, const float* __restrict__ cb,
    const int* __restrict__ order, const int* __restrict__ key,
    float* __restrict__ out6, float* __restrict__ lossp) {
  __shared__ int so[CHUNK], sk[CHUNK];
  __shared__ float red[2];
  const int t = threadIdx.x;
  const int base = blockIdx.x * CHUNK;
  if (t < CHUNK) { so[t] = order[base + t]; sk[t] = key[base + t]; }
  __syncthreads();
  int kprev = sk[0];
  float cbv = cb[kprev * 128 + t];
  float acc = 0.f, loss = 0.f;
  int i = 0;
  while (i < CHUNK) {
    if (i + 8 <= CHUNK && sk[i] == kprev && sk[i + 7] == kprev) {
      // keys non-decreasing: ends equal => whole run equal. 8 loads in flight.
      const int n0 = so[i + 0], n1 = so[i + 1], n2 = so[i + 2], n3 = so[i + 3];
      const int n4 = so[i + 4], n5 = so[i + 5], n6 = so[i + 6], n7 = so[i + 7];
      const float v0 = zq[(size_t)n0 * 128 + t];
      const float v1 = zq[(size_t)n1 * 128 + t];
      const float v2 = zq[(size_t)n2 * 128 + t];
      const float v3 = zq[(size_t)n3 * 128 + t];
      const float v4 = zq[(size_t)n4 * 128 + t];
      const float v5 = zq[(size_t)n5 * 128 + t];
      const float v6 = zq[(size_t)n6 * 128 + t];
      const float v7 = zq[(size_t)n7 * 128 + t];
      acc += ((v0 + v1) + (v2 + v3)) + ((v4 + v5) + (v6 + v7));
      float e;
      e = cbv - v0; loss = fmaf(e, e, loss);
      e = cbv - v1; loss = fmaf(e, e, loss);
      e = cbv - v2; loss = fmaf(e, e, loss);
      e = cbv - v3; loss = fmaf(e, e, loss);
      e = cbv - v4; loss = fmaf(e, e, loss);
      e = cbv - v5; loss = fmaf(e, e, loss);
      e = cbv - v6; loss = fmaf(e, e, loss);
      e = cbv - v7; loss = fmaf(e, e, loss);
      zq[(size_t)n0 * 128 + t] = cbv; zq[(size_t)n1 * 128 + t] = cbv;
      zq[(size_t)n2 * 128 + t] = cbv; zq[(size_t)n3 * 128 + t] = cbv;
      zq[(size_t)n4 * 128 + t] = cbv; zq[(size_t)n5 * 128 + t] = cbv;
      zq[(size_t)n6 * 128 + t] = cbv; zq[(size_t)n7 * 128 + t] = cbv;
      i += 8;
    } else {
      const int kk = sk[i];
      if (kk != kprev) {
        atomicAdd(&out6[kprev * 128 + t], 0.01f * acc);
        acc = 0.f; kprev = kk;
        cbv = cb[kk * 128 + t];
      }
      const int n = so[i];
      const float v = zq[(size_t)n * 128 + t];
      acc += v;
      const float e = cbv - v; loss = fmaf(e, e, loss);
      zq[(size_t)n * 128 + t] = cbv;
      ++i;
    }
  }
  atomicAdd(&out6[kprev * 128 + t], 0.01f * acc);
#pragma unroll
  for (int m = 32; m; m >>= 1) loss += __shfl_xor(loss, m, 64);
  if ((t & 63) == 0) red[t >> 6] = loss;
  __syncthreads();
  if (t == 0) lossp[blockIdx.x] = red[0] + red[1];
}

// ---------------- new_codebook + losses (block 511 reduces partials) -------
__global__ void k_final(const float* __restrict__ out5, const float* __restrict__ out6,
                        const float* __restrict__ ntot_p, const float* __restrict__ lossp,
                        float* __restrict__ out4, float* __restrict__ out2,
                        float* __restrict__ out3) {
  __shared__ float red[4];
  const int i = blockIdx.x * blockDim.x + threadIdx.x;
  const float ntot = *ntot_p;
  const int k = i >> 7;
  const float w = (out5[k] + 1e-5f) / (ntot + KCB * 1e-5f) * ntot;
  out4[i] = out6[i] / w;
  if (blockIdx.x == 511) {
    const int t = threadIdx.x;
    float s = 0.f;
#pragma unroll
    for (int j = 0; j < NCHUNKS / 256; ++j) s += lossp[t + 256 * j];
#pragma unroll
    for (int m = 32; m; m >>= 1) s += __shfl_xor(s, m, 64);
    if ((t & 63) == 0) red[t >> 6] = s;
    __syncthreads();
    if (t == 0) {
      const float lv = (red[0] + red[1] + red[2] + red[3]) * (1.f / 8388608.f);
      *out2 = lv; *out3 = lv;
    }
  }
}

extern "C" void kernel_launch(void* const* d_in, const int* in_sizes, int n_in,
                              void* d_out, int out_size, void* d_ws, size_t ws_size,
                              hipStream_t stream) {
  (void)in_sizes; (void)n_in; (void)out_size; (void)ws_size;
  const float* z   = (const float*)d_in[0];
  const float* cb  = (const float*)d_in[1];
  const float* emc = (const float*)d_in[2];
  const float* emw = (const float*)d_in[3];
  float* out = (float*)d_out;
  float* out0 = out;                    // quantized_st  [8388608]
  float* out1 = out + 8388608;          // idx_map (float)[65536]
  float* out2 = out + 8454144;          // commitment_loss [1]
  float* out3 = out + 8454145;          // codebook_loss   [1]
  float* out4 = out + 8454146;          // new_codebook  [131072]
  float* out5 = out + 8585218;          // new_ema_count [1024]
  float* out6 = out + 8586242;          // new_ema_weight[131072]
  float* ws = (float*)d_ws;
  uint4* cbt      = (uint4*)ws;         // [16384] uint4 = 256KB
  // pcand [2*NVEC] uint2 = 1MB, aliases order/key (scatter runs after rescore)
  uint2* pcand    = (uint2*)(ws + 65536);
  int* order      = (int*)(ws + 65536); // [65536]
  int* key        = (int*)(ws + 131072);// [65536]  (pcand spans through 327680)
  float* ccb      = ws + 327680;        // [1024]
  int* hist       = (int*)(ws + 328704);// [1024]
  int* cursor     = (int*)(ws + 329728);// [1024]
  float* ntot     = ws + 330752;        // [1]
  float* lossp    = ws + 331776;        // [1024]
  double* cc64    = (double*)(ws + 333824);  // [1024] doubles (8B-aligned)
  float* z_t = out0;                    // z_t aliases out0 (overwritten in chunkreduce_q)

  hipLaunchKernelGGL(k_prep, dim3(64), dim3(256), 0, stream, cb, emw, cbt, ccb,
                     cc64, out6, hist);
  hipLaunchKernelGGL(k_argmin3t, dim3(NVEC / 64), dim3(256), 0, stream,
                     z, cbt, ccb, pcand, z_t);
  hipLaunchKernelGGL(k_rescore_hist, dim3(NVEC / 256), dim3(256), 0, stream,
                     z_t, cb, cc64, pcand, out1, hist);
  hipLaunchKernelGGL(k_scan, dim3(1), dim3(1024), 0, stream, hist, emc, cursor,
                     out5, ntot);
  hipLaunchKernelGGL(k_scatter, dim3(NVEC / 256), dim3(256), 0, stream, out1, cursor,
                     order, key);
  hipLaunchKernelGGL(k_chunkreduce_q, dim3(NCHUNKS), dim3(128), 0, stream,
                     z_t, cb, order, key, out6, lossp);
  hipLaunchKernelGGL(k_final, dim3(512), dim3(256), 0, stream, out5, out6, ntot,
                     lossp, out4, out2, out3);
}